// Round 1
// baseline (2528.002 us; speedup 1.0000x reference)
//
#include <hip/hip_runtime.h>
#include <math.h>

#define CIN 256
#define HH 64
#define WW 64
#define HW 4096
#define CHW (CIN * HW) // 1048576

// ================= Kernel A: offset = conv3x3(x, w_off)  (bias folded into consumer) ==============
// grid = B*64 rows, 256 threads. Wave wv handles channel chunk wv*64..+63; lane = w.
__global__ __launch_bounds__(256) void k_offset_conv(
    const float* __restrict__ x, const float* __restrict__ w_off,
    float* __restrict__ off_out)
{
    __shared__ float red[4][64][18];
    const int blk = blockIdx.x;
    const int b = blk >> 6, h = blk & 63;
    const int t = threadIdx.x;
    const int w = t & 63;
    const int wv = __builtin_amdgcn_readfirstlane(t >> 6);
    float acc[18];
#pragma unroll
    for (int i = 0; i < 18; ++i) acc[i] = 0.f;
    const float* xb = x + (size_t)b * CHW;
    for (int ci = 0; ci < 64; ++ci) {
        const int c = wv * 64 + ci;
        const float* xc = xb + (size_t)c * HW;
        float r0 = (h > 0)  ? xc[(h - 1) * WW + w] : 0.f;
        float r1 =            xc[h * WW + w];
        float r2 = (h < 63) ? xc[(h + 1) * WW + w] : 0.f;
        float l0 = __shfl_up(r0, 1), l1 = __shfl_up(r1, 1), l2 = __shfl_up(r2, 1);
        float d0 = __shfl_down(r0, 1), d1 = __shfl_down(r1, 1), d2 = __shfl_down(r2, 1);
        if (w == 0)  { l0 = 0.f; l1 = 0.f; l2 = 0.f; }
        if (w == 63) { d0 = 0.f; d1 = 0.f; d2 = 0.f; }
        const float xv[9] = {l0, r0, d0, l1, r1, d1, l2, r2, d2};
        const float* wc = w_off + (size_t)c * 9;
#pragma unroll
        for (int co = 0; co < 18; ++co) {
            const float* wp = wc + (size_t)co * (CIN * 9);
#pragma unroll
            for (int k = 0; k < 9; ++k) acc[co] += wp[k] * xv[k];
        }
    }
#pragma unroll
    for (int co = 0; co < 18; ++co) red[wv][w][co] = acc[co];
    __syncthreads();
    if (t < 64) {
#pragma unroll
        for (int co = 0; co < 18; ++co) {
            float s = red[0][t][co] + red[1][t][co] + red[2][t][co] + red[3][t][co];
            off_out[((b * 18 + co) * HH + h) * WW + t] = s;
        }
    }
}

// ================= Kernel B: deform-conv for q|k|v (320 output channels, shared samples) ==========
// grid = (64 rows h, 5 co-chunks of 64, B). 256 threads: cg = t>>6 (16 co each), w = t&63.
__global__ __launch_bounds__(256) void k_qkv_deform(
    const float* __restrict__ x, const float* __restrict__ off_buf,
    const float* __restrict__ b_off,
    const float* __restrict__ wq, const float* __restrict__ bq,
    const float* __restrict__ wk, const float* __restrict__ bk,
    const float* __restrict__ wv_, const float* __restrict__ bv,
    float* __restrict__ qbuf, float* __restrict__ kbuf, float* __restrict__ vbuf)
{
    __shared__ float4 wgt[576]; // (k,w) -> 4 bilinear corner weights (validity folded)
    __shared__ int4   adr[576]; // (k,w) -> 4 clipped plane addresses
    __shared__ float  smp[4][64 * 12]; // 4 channels x (w-major, 12-padded taps)

    const int h = blockIdx.x;
    const int chunk = blockIdx.y;
    const int b = blockIdx.z;
    const int t = threadIdx.x;
    const int w = t & 63;
    const int cgu = __builtin_amdgcn_readfirstlane(t >> 6);

    // ---- phase 0: bilinear sampling parameters for this row, all 9 taps x 64 w ----
    for (int r = 0; r < 3; ++r) {
        int sid = t + 256 * r;
        if (sid < 576) {
            int k = sid >> 6, ww = sid & 63;
            float dy = off_buf[((b * 18 + 2 * k) * HH + h) * WW + ww] + b_off[2 * k];
            float dx = off_buf[((b * 18 + 2 * k + 1) * HH + h) * WW + ww] + b_off[2 * k + 1];
            float py = (float)(h + k / 3 - 1) + dy;
            float px = (float)(ww + k % 3 - 1) + dx;
            float y0f = floorf(py), x0f = floorf(px);
            float fy = py - y0f, fx = px - x0f;
            int y0 = (int)y0f, x0 = (int)x0f;
            int y1 = y0 + 1, x1 = x0 + 1;
            float vy0 = (y0 >= 0 && y0 < HH) ? 1.f : 0.f;
            float vy1 = (y1 >= 0 && y1 < HH) ? 1.f : 0.f;
            float vx0 = (x0 >= 0 && x0 < WW) ? 1.f : 0.f;
            float vx1 = (x1 >= 0 && x1 < WW) ? 1.f : 0.f;
            int yc0 = min(max(y0, 0), 63), yc1 = min(max(y1, 0), 63);
            int xc0 = min(max(x0, 0), 63), xc1 = min(max(x1, 0), 63);
            wgt[sid] = make_float4((1.f - fy) * (1.f - fx) * vy0 * vx0,
                                   (1.f - fy) * fx         * vy0 * vx1,
                                   fy         * (1.f - fx) * vy1 * vx0,
                                   fy         * fx         * vy1 * vx1);
            adr[sid] = make_int4(yc0 * WW + xc0, yc0 * WW + xc1,
                                 yc1 * WW + xc0, yc1 * WW + xc1);
        }
    }

    // ---- wave-uniform weight/output selection ----
    const float* wbase; const float* bias; float* obuf; int co0; size_t nper;
    if (chunk == 0) {
        if (cgu < 2) { wbase = wq; bias = bq; obuf = qbuf; co0 = cgu * 16; nper = (size_t)32 * HW; }
        else         { wbase = wk; bias = bk; obuf = kbuf; co0 = (cgu - 2) * 16; nper = (size_t)32 * HW; }
    } else {
        wbase = wv_; bias = bv; obuf = vbuf; co0 = (chunk - 1) * 64 + cgu * 16; nper = (size_t)256 * HW;
    }

    float acc[16];
#pragma unroll
    for (int i = 0; i < 16; ++i) acc[i] = 0.f;
    const float* xb = x + (size_t)b * CHW;
    __syncthreads();

    for (int cb = 0; cb < 64; ++cb) {
        // ---- stage bilinear samples for channels cb*4 .. cb*4+3 ----
#pragma unroll
        for (int r = 0; r < 9; ++r) {
            int sid2 = t + 256 * r;           // 0..2303
            int cl = sid2 / 576;
            int slot = sid2 - cl * 576;
            const float* xc = xb + (size_t)(cb * 4 + cl) * HW;
            float4 wg = wgt[slot]; int4 ad = adr[slot];
            float sv = wg.x * xc[ad.x] + wg.y * xc[ad.y] + wg.z * xc[ad.z] + wg.w * xc[ad.w];
            int kk = slot >> 6, ww2 = slot & 63;
            smp[cl][ww2 * 12 + kk] = sv;
        }
        __syncthreads();
        // ---- FMA: 16 co x 9 taps per channel, weights via scalar loads ----
#pragma unroll
        for (int cl = 0; cl < 4; ++cl) {
            const int c = cb * 4 + cl;
            const float* sp = &smp[cl][w * 12];
            float4 s0 = *(const float4*)sp;
            float4 s1 = *(const float4*)(sp + 4);
            float  s8 = sp[8];
#pragma unroll
            for (int ci = 0; ci < 16; ++ci) {
                const float* wp = wbase + ((size_t)(co0 + ci) * CIN + c) * 9;
                acc[ci] += wp[0] * s0.x + wp[1] * s0.y + wp[2] * s0.z + wp[3] * s0.w
                         + wp[4] * s1.x + wp[5] * s1.y + wp[6] * s1.z + wp[7] * s1.w
                         + wp[8] * s8;
            }
        }
        __syncthreads();
    }

    const size_t base = (size_t)b * nper;
#pragma unroll
    for (int ci = 0; ci < 16; ++ci) {
        int co = co0 + ci;
        obuf[base + (size_t)co * HW + h * WW + w] = acc[ci] + bias[co];
    }
}

// ================= Kernel C: flash attention over flat-reshaped q/k/v + residual epilogue ========
// grid = (128 q-tiles of 32 rows, B). 256 threads.
__global__ __launch_bounds__(256) void k_attn(
    const float* __restrict__ qbuf, const float* __restrict__ kbuf,
    const float* __restrict__ vbuf, const float* __restrict__ x,
    const float* __restrict__ gamma, float* __restrict__ out)
{
    __shared__ float Klds[64 * 36];          // 64 k-rows x 32 d, stride 36 (16B-aligned, low conflict)
    __shared__ float Pl[64 * 34];            // scores/probs: [j][q], stride 34 (8B-aligned)
    __shared__ float Mlds[32], Llds[32], Alds[32];

    const int qt = blockIdx.x, b = blockIdx.y;
    const int t = threadIdx.x;
    const int lane = t & 63;

    const float* Qb = qbuf + (size_t)b * 32 * HW;
    const float* Kb = kbuf + (size_t)b * 32 * HW;
    const float* Vb = vbuf + (size_t)b * 256 * HW;

    // dot-phase mapping: q pair per 16-lane group; 4 j per thread
    const int qp = t >> 4;                   // 0..15
    const int jl = t & 15;
    const int q0 = qp * 2, q1 = q0 + 1;      // local q rows
    float4 qv0[8], qv1[8];
    {
        const float4* qr0 = (const float4*)(Qb + (size_t)(qt * 32 + q0) * 32);
        const float4* qr1 = (const float4*)(Qb + (size_t)(qt * 32 + q1) * 32);
#pragma unroll
        for (int dd = 0; dd < 8; ++dd) { qv0[dd] = qr0[dd]; qv1[dd] = qr1[dd]; }
    }
    if (t < 32) { Mlds[t] = -1e30f; Llds[t] = 0.f; }

    // PV mapping: qg = t>>5 owns 4 q rows; cg = t&31 owns 8 v-columns
    const int cg = t & 31, qg = t >> 5;
    // softmax mapping: row r = t>>3, 8 lanes per row
    const int r = t >> 3, j8 = t & 7;

    float accv[4][8];
#pragma unroll
    for (int i = 0; i < 4; ++i)
#pragma unroll
        for (int c8 = 0; c8 < 8; ++c8) accv[i][c8] = 0.f;

    for (int jt = 0; jt < 64; ++jt) {
        __syncthreads(); // prev PV done before Pl/Klds reuse
        // ---- stage K tile ----
        {
            const float4* Ksrc = (const float4*)(Kb + (size_t)jt * 64 * 32);
#pragma unroll
            for (int r2 = 0; r2 < 2; ++r2) {
                int f4 = t + 256 * r2;            // 0..511
                float4 kv = Ksrc[f4];
                int row = f4 >> 3, col = (f4 & 7) * 4;
                *(float4*)&Klds[row * 36 + col] = kv;
            }
        }
        __syncthreads();
        // ---- S = Q K^T for this tile ----
#pragma unroll
        for (int jj = 0; jj < 4; ++jj) {
            int j = jl + 16 * jj;
            float d0 = 0.f, d1 = 0.f;
#pragma unroll
            for (int dd = 0; dd < 8; ++dd) {
                float4 kv = *(const float4*)&Klds[j * 36 + dd * 4];
                d0 += qv0[dd].x * kv.x + qv0[dd].y * kv.y + qv0[dd].z * kv.z + qv0[dd].w * kv.w;
                d1 += qv1[dd].x * kv.x + qv1[dd].y * kv.y + qv1[dd].z * kv.z + qv1[dd].w * kv.w;
            }
            Pl[j * 34 + q0] = d0;
            Pl[j * 34 + q1] = d1;
        }
        __syncthreads();
        // ---- online softmax (per row, 8 lanes each) ----
        {
            float sv[8]; float mx = -1e30f;
#pragma unroll
            for (int m = 0; m < 8; ++m) { sv[m] = Pl[(j8 + 8 * m) * 34 + r]; mx = fmaxf(mx, sv[m]); }
            mx = fmaxf(mx, __shfl_xor(mx, 1));
            mx = fmaxf(mx, __shfl_xor(mx, 2));
            mx = fmaxf(mx, __shfl_xor(mx, 4));
            float Mnew = 0.f, alpha = 0.f;
            if (j8 == 0) {
                float Mold = Mlds[r];
                Mnew = fmaxf(Mold, mx);
                alpha = __expf(Mold - Mnew);
            }
            Mnew = __shfl(Mnew, lane & 56);
            float ls = 0.f;
#pragma unroll
            for (int m = 0; m < 8; ++m) {
                float p = __expf(sv[m] - Mnew);
                Pl[(j8 + 8 * m) * 34 + r] = p;
                ls += p;
            }
            ls += __shfl_xor(ls, 1); ls += __shfl_xor(ls, 2); ls += __shfl_xor(ls, 4);
            if (j8 == 0) {
                Mlds[r] = Mnew;
                Alds[r] = alpha;
                Llds[r] = Llds[r] * alpha + ls;
            }
        }
        __syncthreads();
        // ---- PV accumulate ----
        {
            float al[4];
#pragma unroll
            for (int i = 0; i < 4; ++i) al[i] = Alds[qg * 4 + i];
#pragma unroll
            for (int i = 0; i < 4; ++i)
#pragma unroll
                for (int c8 = 0; c8 < 8; ++c8) accv[i][c8] *= al[i];
            const float* vb2 = Vb + (size_t)jt * 64 * 256 + cg * 8;
#pragma unroll 4
            for (int j = 0; j < 64; ++j) {
                const float* vr = vb2 + j * 256;
                float4 v0 = *(const float4*)vr;
                float4 v1 = *(const float4*)(vr + 4);
                float2 pa = *(const float2*)&Pl[j * 34 + qg * 4];
                float2 pb = *(const float2*)&Pl[j * 34 + qg * 4 + 2];
                const float pw[4] = {pa.x, pa.y, pb.x, pb.y};
                const float vv[8] = {v0.x, v0.y, v0.z, v0.w, v1.x, v1.y, v1.z, v1.w};
#pragma unroll
                for (int i = 0; i < 4; ++i)
#pragma unroll
                    for (int c8 = 0; c8 < 8; ++c8)
                        accv[i][c8] += pw[i] * vv[c8];
            }
        }
    }
    __syncthreads();
    // ---- epilogue: out = gamma * (acc / L) + x, flat-reshape linear indexing ----
    const float g = gamma[0];
    const float* xb = x + (size_t)b * CHW;
    float* ob = out + (size_t)b * CHW;
#pragma unroll
    for (int i = 0; i < 4; ++i) {
        int q = qg * 4 + i;
        float inv = 1.f / Llds[q];
        size_t m = (size_t)(qt * 32 + q) * 256 + cg * 8;
        float4 xa = *(const float4*)(xb + m);
        float4 xc = *(const float4*)(xb + m + 4);
        float4 o0, o1;
        o0.x = g * accv[i][0] * inv + xa.x;
        o0.y = g * accv[i][1] * inv + xa.y;
        o0.z = g * accv[i][2] * inv + xa.z;
        o0.w = g * accv[i][3] * inv + xa.w;
        o1.x = g * accv[i][4] * inv + xc.x;
        o1.y = g * accv[i][5] * inv + xc.y;
        o1.z = g * accv[i][6] * inv + xc.z;
        o1.w = g * accv[i][7] * inv + xc.w;
        *(float4*)(ob + m) = o0;
        *(float4*)(ob + m + 4) = o1;
    }
}

extern "C" void kernel_launch(void* const* d_in, const int* in_sizes, int n_in,
                              void* d_out, int out_size, void* d_ws, size_t ws_size,
                              hipStream_t stream)
{
    (void)in_sizes; (void)n_in; (void)out_size; (void)ws_size;
    const float* x     = (const float*)d_in[0];
    const float* w_off = (const float*)d_in[1];
    const float* b_off = (const float*)d_in[2];
    const float* wq    = (const float*)d_in[3];
    const float* bq    = (const float*)d_in[4];
    const float* wk    = (const float*)d_in[5];
    const float* bk    = (const float*)d_in[6];
    const float* wv    = (const float*)d_in[7];
    const float* bv    = (const float*)d_in[8];
    const float* gamma = (const float*)d_in[9];
    float* out = (float*)d_out;

    float* off_buf = (float*)d_ws;                 // 2*18*4096  = 147456 floats
    float* qbuf = off_buf + 2 * 18 * HW;           // 2*32*4096  = 262144
    float* kbuf = qbuf + 2 * 32 * HW;              // 262144
    float* vbuf = kbuf + 2 * 32 * HW;              // 2*256*4096 = 2097152  (total ~10.6 MB)

    k_offset_conv<<<dim3(2 * HH), 256, 0, stream>>>(x, w_off, off_buf);
    k_qkv_deform<<<dim3(HH, 5, 2), 256, 0, stream>>>(x, off_buf, b_off,
                                                     wq, bq, wk, bk, wv, bv,
                                                     qbuf, kbuf, vbuf);
    k_attn<<<dim3(128, 2), 256, 0, stream>>>(qbuf, kbuf, vbuf, x, gamma, out);
}

// Round 2
// 672.772 us; speedup vs baseline: 3.7576x; 3.7576x over previous
//
#include <hip/hip_runtime.h>
#include <math.h>
#include <stdint.h>

#define CIN 256
#define HH 64
#define WW 64
#define HW 4096
#define CHW (CIN * HW) // 1048576

typedef __attribute__((ext_vector_type(8))) short short8;   // 8 bf16 = 4 VGPR (MFMA A/B frag)
typedef __attribute__((ext_vector_type(4))) float float4v;  // MFMA C/D frag

__device__ inline unsigned short f2bf(float f) {
    union { float f; uint32_t u; } v; v.f = f;
    return (unsigned short)((v.u + 0x7FFFu + ((v.u >> 16) & 1u)) >> 16);
}
__device__ inline float bf2f(unsigned short h) {
    union { uint32_t u; float f; } v; v.u = ((uint32_t)h) << 16;
    return v.f;
}

// ================= Kernel 1: offset = conv3x3(x, w_off) (fp32; bias folded into K2) ==============
__global__ __launch_bounds__(256) void k_offset_conv(
    const float* __restrict__ x, const float* __restrict__ w_off,
    float* __restrict__ off_out)
{
    __shared__ float red[4][64][18];
    const int blk = blockIdx.x;
    const int b = blk >> 6, h = blk & 63;
    const int t = threadIdx.x;
    const int w = t & 63;
    const int wv = __builtin_amdgcn_readfirstlane(t >> 6);
    float acc[18];
#pragma unroll
    for (int i = 0; i < 18; ++i) acc[i] = 0.f;
    const float* xb = x + (size_t)b * CHW;
    for (int ci = 0; ci < 64; ++ci) {
        const int c = wv * 64 + ci;
        const float* xc = xb + (size_t)c * HW;
        float r0 = (h > 0)  ? xc[(h - 1) * WW + w] : 0.f;
        float r1 =            xc[h * WW + w];
        float r2 = (h < 63) ? xc[(h + 1) * WW + w] : 0.f;
        float l0 = __shfl_up(r0, 1), l1 = __shfl_up(r1, 1), l2 = __shfl_up(r2, 1);
        float d0 = __shfl_down(r0, 1), d1 = __shfl_down(r1, 1), d2 = __shfl_down(r2, 1);
        if (w == 0)  { l0 = 0.f; l1 = 0.f; l2 = 0.f; }
        if (w == 63) { d0 = 0.f; d1 = 0.f; d2 = 0.f; }
        const float xv[9] = {l0, r0, d0, l1, r1, d1, l2, r2, d2};
        const float* wc = w_off + (size_t)c * 9;
#pragma unroll
        for (int co = 0; co < 18; ++co) {
            const float* wp = wc + (size_t)co * (CIN * 9);
#pragma unroll
            for (int k = 0; k < 9; ++k) acc[co] += wp[k] * xv[k];
        }
    }
#pragma unroll
    for (int co = 0; co < 18; ++co) red[wv][w][co] = acc[co];
    __syncthreads();
    if (t < 64) {
#pragma unroll
        for (int co = 0; co < 18; ++co) {
            float s = red[0][t][co] + red[1][t][co] + red[2][t][co] + red[3][t][co];
            off_out[((b * 18 + co) * HH + h) * WW + t] = s;
        }
    }
}

// ================= Kernel 2: bilinear params (bf16 wgt x4 + u16 addr x4, 16B per (tap,pixel)) ====
// grid 128 = b*64+h, 256 threads; 576 sets per row.
__global__ __launch_bounds__(256) void k_params(
    const float* __restrict__ off_buf, const float* __restrict__ b_off,
    uint4* __restrict__ pbuf)
{
    const int bh = blockIdx.x;
    const int b = bh >> 6, h = bh & 63;
    const int t = threadIdx.x;
    for (int r = 0; r < 3; ++r) {
        int sid = t + 256 * r;
        if (sid < 576) {
            int k = sid >> 6, ww = sid & 63;
            float dy = off_buf[((b * 18 + 2 * k) * HH + h) * WW + ww] + b_off[2 * k];
            float dx = off_buf[((b * 18 + 2 * k + 1) * HH + h) * WW + ww] + b_off[2 * k + 1];
            float py = (float)(h + k / 3 - 1) + dy;
            float px = (float)(ww + k % 3 - 1) + dx;
            float y0f = floorf(py), x0f = floorf(px);
            float fy = py - y0f, fx = px - x0f;
            int y0 = (int)y0f, x0 = (int)x0f, y1 = y0 + 1, x1 = x0 + 1;
            float vy0 = (y0 >= 0 && y0 < HH) ? 1.f : 0.f;
            float vy1 = (y1 >= 0 && y1 < HH) ? 1.f : 0.f;
            float vx0 = (x0 >= 0 && x0 < WW) ? 1.f : 0.f;
            float vx1 = (x1 >= 0 && x1 < WW) ? 1.f : 0.f;
            int yc0 = min(max(y0, 0), 63), yc1 = min(max(y1, 0), 63);
            int xc0 = min(max(x0, 0), 63), xc1 = min(max(x1, 0), 63);
            uint4 pk;
            pk.x = (uint32_t)f2bf((1.f - fy) * (1.f - fx) * vy0 * vx0)
                 | ((uint32_t)f2bf((1.f - fy) * fx * vy0 * vx1) << 16);
            pk.y = (uint32_t)f2bf(fy * (1.f - fx) * vy1 * vx0)
                 | ((uint32_t)f2bf(fy * fx * vy1 * vx1) << 16);
            pk.z = (uint32_t)(yc0 * WW + xc0) | ((uint32_t)(yc0 * WW + xc1) << 16);
            pk.w = (uint32_t)(yc1 * WW + xc0) | ((uint32_t)(yc1 * WW + xc1) << 16);
            pbuf[(size_t)bh * 576 + sid] = pk;
        }
    }
}

// ================= Kernel 3: fused sample + MFMA GEMM: [320 co] x [2304 k] x [64 n per block] ====
// grid (128 n-tiles = b*64+h, 5 m-tiles of 64). 256 threads = 4 waves; wave = 16 co rows.
__global__ __launch_bounds__(256) void k_deform_gemm(
    const float* __restrict__ x, const uint4* __restrict__ pbuf,
    const float* __restrict__ wq, const float* __restrict__ bq,
    const float* __restrict__ wk, const float* __restrict__ bk,
    const float* __restrict__ wv, const float* __restrict__ bv,
    unsigned short* __restrict__ qb16, unsigned short* __restrict__ kb16,
    unsigned short* __restrict__ vb16)
{
    __shared__ uint4 prm[576];                 // 9216 B bilinear params (tap*64 + w)
    __shared__ unsigned short Bt[64][40];      // S-tile, n-major, k-contiguous, padded (5120 B)

    const int nt = blockIdx.x;                 // b*64 + h
    const int mt = blockIdx.y;
    const int b = nt >> 6;
    const int t = threadIdx.x;
    const int lane = t & 63;
    const int l15 = lane & 15, quad = lane >> 4;
    const int wv_id = __builtin_amdgcn_readfirstlane(t >> 6);

    for (int r = 0; r < 3; ++r) {
        int sid = t + 256 * r;
        if (sid < 576) prm[sid] = pbuf[(size_t)nt * 576 + sid];
    }

    // wave-uniform output-array select (16-row strips never cross q/k/v boundaries)
    const int cobase = mt * 64 + wv_id * 16;
    const float* wl; const float* bl; unsigned short* ob; int lco; size_t nper;
    if (cobase < 32)      { wl = wq; bl = bq; ob = qb16; lco = cobase;      nper = (size_t)32 * HW; }
    else if (cobase < 64) { wl = wk; bl = bk; ob = kb16; lco = cobase - 32; nper = (size_t)32 * HW; }
    else                  { wl = wv; bl = bv; ob = vb16; lco = cobase - 64; nper = (size_t)256 * HW; }

    // A-frag source: row m = lane&15, k = quad*8 + j (fp32, cvt to bf16 per k-step)
    const float* wrow = wl + (size_t)(lco + l15) * 2304 + quad * 8;

    const float* xb = x + (size_t)b * CHW;
    const int nl = t & 63;     // n-local (pixel w)
    const int oct = t >> 6;    // k-octet within the 32-k step

    float4v acc[4];
#pragma unroll
    for (int s = 0; s < 4; ++s) acc[s] = (float4v){0.f, 0.f, 0.f, 0.f};

    __syncthreads();

    for (int k0 = 0; k0 < 2304; k0 += 32) {
        // --- A loads (independent, overlap sampling) ---
        float4 a0 = *(const float4*)(wrow + k0);
        float4 a1 = *(const float4*)(wrow + k0 + 16);  // +16 k -> next 8-group at same quad? NO
        // NOTE: lane covers k = quad*8 + [0..7] only; the frag is 8 consecutive k starting quad*8.
        // a0 = k0+quad*8+0..3, a1 = k0+quad*8+4..7:
        a1 = *(const float4*)(wrow + k0 + 4);

        // --- sample 8 values: k_local = oct*8 + kk, n = nl ---
        unsigned short sm[8];
#pragma unroll
        for (int kk = 0; kk < 8; ++kk) {
            int kd = k0 + oct * 8 + kk;
            int c = (kd * 7282) >> 16;      // exact /9 for kd < 2304
            int tap = kd - c * 9;
            uint4 pk = prm[tap * 64 + nl];
            const float* xp = xb + (size_t)c * HW;
            float g0 = xp[pk.z & 0xFFFF], g1 = xp[pk.z >> 16];
            float g2 = xp[pk.w & 0xFFFF], g3 = xp[pk.w >> 16];
            float s = bf2f((unsigned short)(pk.x & 0xFFFF)) * g0
                    + bf2f((unsigned short)(pk.x >> 16)) * g1
                    + bf2f((unsigned short)(pk.y & 0xFFFF)) * g2
                    + bf2f((unsigned short)(pk.y >> 16)) * g3;
            sm[kk] = f2bf(s);
        }
        __syncthreads();   // WAR: previous iteration's frag reads done
        *(uint4*)&Bt[nl][oct * 8] = *(const uint4*)sm;
        __syncthreads();   // RAW: tile visible

        // --- A frag to bf16 ---
        union { short8 v; unsigned short u[8]; } A;
        A.u[0] = f2bf(a0.x); A.u[1] = f2bf(a0.y); A.u[2] = f2bf(a0.z); A.u[3] = f2bf(a0.w);
        A.u[4] = f2bf(a1.x); A.u[5] = f2bf(a1.y); A.u[6] = f2bf(a1.z); A.u[7] = f2bf(a1.w);

#pragma unroll
        for (int s = 0; s < 4; ++s) {
            short8 bfr = *(const short8*)&Bt[s * 16 + l15][quad * 8];
            acc[s] = __builtin_amdgcn_mfma_f32_16x16x32_bf16(A.v, bfr, acc[s], 0, 0, 0);
        }
    }

    // --- epilogue: bias + bf16 store to flat [co][p] buffers ---
    const int pbase = (nt & 63) * 64;   // h*64
    float bias_r[4];
#pragma unroll
    for (int r = 0; r < 4; ++r) bias_r[r] = bl[lco + (quad << 2) + r];
    unsigned short* obb = ob + (size_t)b * nper;
#pragma unroll
    for (int s = 0; s < 4; ++s) {
#pragma unroll
        for (int r = 0; r < 4; ++r) {
            int col = lco + (quad << 2) + r;
            obb[(size_t)col * HW + pbase + s * 16 + l15] = f2bf(acc[s][r] + bias_r[r]);
        }
    }
}

// ================= Kernel 4: V transpose: vb16 [j][cc] -> vb16T [cc][j] ==========================
// grid (64 j-tiles of 64, B); 256 threads = one cc each.
__global__ __launch_bounds__(256) void k_vtrans(
    const unsigned short* __restrict__ vb16, unsigned short* __restrict__ vb16T)
{
    const int jt = blockIdx.x, b = blockIdx.y;
    const int cc = threadIdx.x;
    const unsigned short* src = vb16 + (size_t)b * CHW + (size_t)(jt * 64) * 256 + cc;
    unsigned short* dst = vb16T + (size_t)b * CHW + (size_t)cc * 4096 + jt * 64;
#pragma unroll
    for (int o = 0; o < 8; ++o) {
        union { uint4 v; unsigned short u[8]; } tmp;
#pragma unroll
        for (int j = 0; j < 8; ++j) tmp.u[j] = src[(o * 8 + j) * 256];  // coalesced over cc
        *(uint4*)(dst + o * 8) = tmp.v;  // lane-contiguous 128B per thread across o
    }
}

// ================= Kernel 5: barrier-free flash attention (bf16 MFMA) + residual epilogue ========
// grid (128 q-tiles of 32, B); 512 threads = 8 waves: g = wv>>2 (q-group of 16), qu = wv&3 (64 cc).
__global__ __launch_bounds__(512) void k_attn(
    const unsigned short* __restrict__ qb16, const unsigned short* __restrict__ kb16,
    const unsigned short* __restrict__ vb16T, const float* __restrict__ x,
    const float* __restrict__ gamma, float* __restrict__ out)
{
    __shared__ unsigned short pt[8][16 * 40];   // per-wave P buffer (A-layout), 10240 B

    const int qt = blockIdx.x, b = blockIdx.y;
    const int t = threadIdx.x;
    const int lane = t & 63;
    const int wv = t >> 6;
    const int g = wv >> 2, qu = wv & 3;
    const int l15 = lane & 15, quad = lane >> 4;

    const unsigned short* Qb = qb16 + (size_t)b * 32 * HW;
    const unsigned short* Kb = kb16 + (size_t)b * 32 * HW;
    const unsigned short* VT = vb16T + (size_t)b * CHW;

    const int q0 = qt * 32 + g * 16;
    // Q as B-operand of S^T: lane: q = q0+l15, d = quad*8..+7 (flat layout => direct 16B load)
    short8 qfr = *(const short8*)(Qb + (size_t)(q0 + l15) * 32 + quad * 8);

    float m_i = -1e30f, l_i = 0.f;   // per-lane state for q = q0 + l15 (replicated over quads)
    float4v acc[4];
#pragma unroll
    for (int s = 0; s < 4; ++s) acc[s] = (float4v){0.f, 0.f, 0.f, 0.f};
    unsigned short* ptw = pt[wv];

    for (int jt = 0; jt < 128; ++jt) {
        const int j0 = jt * 32;
        // ---- S^T = K Q^T (two 16-j subtiles); rows j = quad*4+reg, cols q = l15 ----
        short8 kfr0 = *(const short8*)(Kb + (size_t)(j0 + l15) * 32 + quad * 8);
        short8 kfr1 = *(const short8*)(Kb + (size_t)(j0 + 16 + l15) * 32 + quad * 8);
        float4v s0 = (float4v){0.f, 0.f, 0.f, 0.f}, s1 = s0;
        s0 = __builtin_amdgcn_mfma_f32_16x16x32_bf16(kfr0, qfr, s0, 0, 0, 0);
        s1 = __builtin_amdgcn_mfma_f32_16x16x32_bf16(kfr1, qfr, s1, 0, 0, 0);
        // ---- online softmax over the 32 j in-tile, per q column ----
        float mx = fmaxf(fmaxf(fmaxf(s0[0], s0[1]), fmaxf(s0[2], s0[3])),
                         fmaxf(fmaxf(s1[0], s1[1]), fmaxf(s1[2], s1[3])));
        mx = fmaxf(mx, __shfl_xor(mx, 16));
        mx = fmaxf(mx, __shfl_xor(mx, 32));
        float mnew = fmaxf(m_i, mx);
        float alpha = __expf(m_i - mnew);
        float p[8]; float ls = 0.f;
#pragma unroll
        for (int r = 0; r < 4; ++r) { p[r] = __expf(s0[r] - mnew); ls += p[r]; }
#pragma unroll
        for (int r = 0; r < 4; ++r) { p[4 + r] = __expf(s1[r] - mnew); ls += p[4 + r]; }
        ls += __shfl_xor(ls, 16);
        ls += __shfl_xor(ls, 32);
        l_i = l_i * alpha + ls;
        m_i = mnew;
        // ---- P -> wave-private LDS in A-layout: pt[q=l15][j_local] ----
        union { uint2 v; unsigned short u[4]; } pk0, pk1;
#pragma unroll
        for (int r = 0; r < 4; ++r) { pk0.u[r] = f2bf(p[r]); pk1.u[r] = f2bf(p[4 + r]); }
        *(uint2*)&ptw[l15 * 40 + quad * 4] = pk0.v;        // j_local = quad*4 + r
        *(uint2*)&ptw[l15 * 40 + 16 + quad * 4] = pk1.v;   // j_local = 16 + quad*4 + r
        // ---- rescale acc rows by alpha (row q-local = quad*4+reg lives in lane quad*4+r) ----
        float ar[4];
#pragma unroll
        for (int r = 0; r < 4; ++r) ar[r] = __shfl(alpha, (quad << 2) + r);
#pragma unroll
        for (int s = 0; s < 4; ++s) {
            acc[s][0] *= ar[0]; acc[s][1] *= ar[1]; acc[s][2] *= ar[2]; acc[s][3] *= ar[3];
        }
        // ---- PV: A = P (m=q, k=j), B = V^T direct-global (k=j contig per cc) ----
        short8 pfr = *(const short8*)&ptw[l15 * 40 + quad * 8];
#pragma unroll
        for (int s = 0; s < 4; ++s) {
            int cc = qu * 64 + s * 16 + l15;
            short8 vfr = *(const short8*)(VT + (size_t)cc * 4096 + j0 + quad * 8);
            acc[s] = __builtin_amdgcn_mfma_f32_16x16x32_bf16(pfr, vfr, acc[s], 0, 0, 0);
        }
    }

    // ---- epilogue: out = gamma * acc/l + x (flat index q*256+cc == c*4096+p) ----
    float lr[4];
#pragma unroll
    for (int r = 0; r < 4; ++r) lr[r] = __shfl(l_i, (quad << 2) + r);
    const float gm = gamma[0];
    const float* xb = x + (size_t)b * CHW;
    float* ob = out + (size_t)b * CHW;
#pragma unroll
    for (int s = 0; s < 4; ++s) {
#pragma unroll
        for (int r = 0; r < 4; ++r) {
            int q = q0 + (quad << 2) + r;
            int cc = qu * 64 + s * 16 + l15;
            size_t idx = (size_t)q * 256 + cc;
            ob[idx] = gm * (acc[s][r] / lr[r]) + xb[idx];
        }
    }
}

extern "C" void kernel_launch(void* const* d_in, const int* in_sizes, int n_in,
                              void* d_out, int out_size, void* d_ws, size_t ws_size,
                              hipStream_t stream)
{
    (void)in_sizes; (void)n_in; (void)out_size; (void)ws_size;
    const float* x     = (const float*)d_in[0];
    const float* w_off = (const float*)d_in[1];
    const float* b_off = (const float*)d_in[2];
    const float* wq    = (const float*)d_in[3];
    const float* bq    = (const float*)d_in[4];
    const float* wk    = (const float*)d_in[5];
    const float* bk    = (const float*)d_in[6];
    const float* wv    = (const float*)d_in[7];
    const float* bv    = (const float*)d_in[8];
    const float* gamma = (const float*)d_in[9];
    float* out = (float*)d_out;

    // ws layout (bytes, 16B-aligned): total ~7.0 MB
    char* ws = (char*)d_ws;
    float*          off_buf = (float*)(ws + 0);                  // 2*18*4096*4   = 589824
    uint4*          pbuf    = (uint4*)(ws + 589824);             // 2*4096*9*16   = 1179648
    unsigned short* qb16    = (unsigned short*)(ws + 1769472);   // 2*32*4096*2   = 524288
    unsigned short* kb16    = (unsigned short*)(ws + 2293760);   // 524288
    unsigned short* vb16T   = (unsigned short*)(ws + 2818048);   // 2*256*4096*2  = 4194304
    // vb16 (natural layout) lives in d_out scratch (4 MB of its 8 MB); K5 overwrites all of d_out.
    unsigned short* vb16    = (unsigned short*)d_out;

    k_offset_conv<<<dim3(2 * HH), 256, 0, stream>>>(x, w_off, off_buf);
    k_params<<<dim3(2 * HH), 256, 0, stream>>>(off_buf, b_off, pbuf);
    k_deform_gemm<<<dim3(2 * HH, 5), 256, 0, stream>>>(x, pbuf, wq, bq, wk, bk, wv, bv,
                                                       qb16, kb16, vb16);
    k_vtrans<<<dim3(64, 2), 256, 0, stream>>>(vb16, vb16T);
    k_attn<<<dim3(128, 2), 512, 0, stream>>>(qb16, kb16, vb16T, x, gamma, out);
}

// Round 3
// 441.593 us; speedup vs baseline: 5.7247x; 1.5235x over previous
//
#include <hip/hip_runtime.h>
#include <math.h>
#include <stdint.h>

#define CIN 256
#define HH 64
#define WW 64
#define HW 4096
#define CHW (CIN * HW) // 1048576

typedef __attribute__((ext_vector_type(8))) short short8;   // 8 bf16 = 4 VGPR (MFMA A/B frag)
typedef __attribute__((ext_vector_type(4))) float float4v;  // MFMA C/D frag
typedef __attribute__((ext_vector_type(2))) float f2a;

__device__ inline unsigned short f2bf(float f) {
    union { float f; uint32_t u; } v; v.f = f;
    return (unsigned short)((v.u + 0x7FFFu + ((v.u >> 16) & 1u)) >> 16);
}
__device__ inline float bf2f(unsigned short h) {
    union { uint32_t u; float f; } v; v.u = ((uint32_t)h) << 16;
    return v.f;
}
__device__ inline f2a ldg2(const float* p) {   // 8B load, 4B-aligned OK on gfx9+
    f2a r; __builtin_memcpy(&r, p, 8); return r;
}

// ================= Kernel 1: offset = conv3x3(x, w_off) (fp32) ===================================
__global__ __launch_bounds__(256) void k_offset_conv(
    const float* __restrict__ x, const float* __restrict__ w_off,
    float* __restrict__ off_out)
{
    __shared__ float red[4][64][18];
    const int blk = blockIdx.x;
    const int b = blk >> 6, h = blk & 63;
    const int t = threadIdx.x;
    const int w = t & 63;
    const int wv = __builtin_amdgcn_readfirstlane(t >> 6);
    float acc[18];
#pragma unroll
    for (int i = 0; i < 18; ++i) acc[i] = 0.f;
    const float* xb = x + (size_t)b * CHW;
    for (int ci = 0; ci < 64; ++ci) {
        const int c = wv * 64 + ci;
        const float* xc = xb + (size_t)c * HW;
        float r0 = (h > 0)  ? xc[(h - 1) * WW + w] : 0.f;
        float r1 =            xc[h * WW + w];
        float r2 = (h < 63) ? xc[(h + 1) * WW + w] : 0.f;
        float l0 = __shfl_up(r0, 1), l1 = __shfl_up(r1, 1), l2 = __shfl_up(r2, 1);
        float d0 = __shfl_down(r0, 1), d1 = __shfl_down(r1, 1), d2 = __shfl_down(r2, 1);
        if (w == 0)  { l0 = 0.f; l1 = 0.f; l2 = 0.f; }
        if (w == 63) { d0 = 0.f; d1 = 0.f; d2 = 0.f; }
        const float xv[9] = {l0, r0, d0, l1, r1, d1, l2, r2, d2};
        const float* wc = w_off + (size_t)c * 9;
#pragma unroll
        for (int co = 0; co < 18; ++co) {
            const float* wp = wc + (size_t)co * (CIN * 9);
#pragma unroll
            for (int k = 0; k < 9; ++k) acc[co] += wp[k] * xv[k];
        }
    }
#pragma unroll
    for (int co = 0; co < 18; ++co) red[wv][w][co] = acc[co];
    __syncthreads();
    if (t < 64) {
#pragma unroll
        for (int co = 0; co < 18; ++co) {
            float s = red[0][t][co] + red[1][t][co] + red[2][t][co] + red[3][t][co];
            off_out[((b * 18 + co) * HH + h) * WW + t] = s;
        }
    }
}

// ================= Kernel 2: patch-form bilinear params ==========================================
// 2x2 patch at (yb,xb), yb,xb in [0,62]; 4 bf16 weights fold tap offset, frac, and border validity.
__global__ __launch_bounds__(256) void k_params(
    const float* __restrict__ off_buf, const float* __restrict__ b_off,
    uint2* __restrict__ pbw, uint32_t* __restrict__ pba)
{
    const int bh = blockIdx.x;
    const int b = bh >> 6, h = bh & 63;
    const int t = threadIdx.x;
    for (int r = 0; r < 3; ++r) {
        int sid = t + 256 * r;
        if (sid < 576) {
            int k = sid >> 6, ww = sid & 63;
            float dy = off_buf[((b * 18 + 2 * k) * HH + h) * WW + ww] + b_off[2 * k];
            float dx = off_buf[((b * 18 + 2 * k + 1) * HH + h) * WW + ww] + b_off[2 * k + 1];
            float py = (float)(h + k / 3 - 1) + dy;
            float px = (float)(ww + k % 3 - 1) + dx;
            float y0f = floorf(py), x0f = floorf(px);
            float fy = py - y0f, fx = px - x0f;
            int y0 = (int)y0f, x0 = (int)x0f;
            int yb = min(max(y0, 0), 62), xb = min(max(x0, 0), 62);
            float wr[2] = {0.f, 0.f}, wc[2] = {0.f, 0.f};
            if (y0 >= 0 && y0 < HH) wr[y0 - yb] += 1.f - fy;
            if (y0 + 1 >= 0 && y0 + 1 < HH) wr[y0 + 1 - yb] += fy;
            if (x0 >= 0 && x0 < WW) wc[x0 - xb] += 1.f - fx;
            if (x0 + 1 >= 0 && x0 + 1 < WW) wc[x0 + 1 - xb] += fx;
            uint2 pw;
            pw.x = (uint32_t)f2bf(wr[0] * wc[0]) | ((uint32_t)f2bf(wr[0] * wc[1]) << 16);
            pw.y = (uint32_t)f2bf(wr[1] * wc[0]) | ((uint32_t)f2bf(wr[1] * wc[1]) << 16);
            pbw[(size_t)bh * 576 + sid] = pw;
            pba[(size_t)bh * 576 + sid] = (uint32_t)(yb * WW + xb);
        }
    }
}

// ================= Kernel 3: W concat + bf16 cast ================================================
__global__ __launch_bounds__(256) void k_wcat(
    const float* __restrict__ wq, const float* __restrict__ wk, const float* __restrict__ wv_,
    const float* __restrict__ bq, const float* __restrict__ bk, const float* __restrict__ bv,
    unsigned short* __restrict__ wcat, float* __restrict__ bcat)
{
    int e = (blockIdx.x * 256 + threadIdx.x) * 4;   // 720 blocks x 256 x 4 = 737280 exact
    const float* src;
    if (e < 32 * 2304)      src = wq + e;
    else if (e < 64 * 2304) src = wk + (e - 32 * 2304);
    else                    src = wv_ + (e - 64 * 2304);
    float4 v = *(const float4*)src;
    unsigned short o[4] = {f2bf(v.x), f2bf(v.y), f2bf(v.z), f2bf(v.w)};
    *(uint2*)(wcat + e) = *(const uint2*)o;
    if (blockIdx.x == 0 && threadIdx.x < 320) {
        int c = threadIdx.x;
        bcat[c] = c < 32 ? bq[c] : (c < 64 ? bk[c - 32] : bv[c - 64]);
    }
}

// ================= Kernel 4: sample S[n=8192][k=2304] bf16, n-major k-contiguous =================
// grid (bh in [0,128), cg in [0,4)); 256 thr: p = t&63 (pixel in row), duo = t>>6 (2 channels).
__global__ __launch_bounds__(256) void k_sample(
    const float* __restrict__ x, const uint2* __restrict__ pbw,
    const uint32_t* __restrict__ pba, unsigned short* __restrict__ sbuf)
{
    __shared__ uint2 prw[576];
    __shared__ uint32_t pra[576];
    __shared__ uint32_t T32[64 * 37];   // 64 pixels x 36 words (72 k bf16) + pad

    const int bh = blockIdx.x;
    const int cg = blockIdx.y;
    const int b = bh >> 6;
    const int t = threadIdx.x;
    const int p = t & 63;
    const int duo = t >> 6;

    for (int r = 0; r < 3; ++r) {
        int sid = t + 256 * r;
        if (sid < 576) { prw[sid] = pbw[(size_t)bh * 576 + sid]; pra[sid] = pba[(size_t)bh * 576 + sid]; }
    }
    __syncthreads();

    const float* xb = x + (size_t)b * CHW;
    const int fr = t >> 2, fc = t & 3;
    uint32_t* sb32 = (uint32_t*)sbuf;

    for (int c8 = 0; c8 < 8; ++c8) {
        const int ca = cg * 64 + c8 * 8 + duo * 2;
        const float* xpa = xb + (size_t)ca * HW;
        const float* xpb = xpa + HW;
        unsigned short vals[18];
#pragma unroll
        for (int tap = 0; tap < 9; ++tap) {
            uint2 wv2 = prw[tap * 64 + p];
            uint32_t base = pra[tap * 64 + p];
            float w00 = bf2f((unsigned short)(wv2.x & 0xFFFF));
            float w01 = bf2f((unsigned short)(wv2.x >> 16));
            float w10 = bf2f((unsigned short)(wv2.y & 0xFFFF));
            float w11 = bf2f((unsigned short)(wv2.y >> 16));
            f2a a0 = ldg2(xpa + base), a1 = ldg2(xpa + base + WW);
            f2a b0 = ldg2(xpb + base), b1 = ldg2(xpb + base + WW);
            vals[tap]     = f2bf(w00 * a0.x + w01 * a0.y + w10 * a1.x + w11 * a1.y);
            vals[9 + tap] = f2bf(w00 * b0.x + w01 * b0.y + w10 * b1.x + w11 * b1.y);
        }
        __syncthreads();  // WAR: previous flush reads done
#pragma unroll
        for (int i = 0; i < 9; ++i)
            T32[p * 37 + duo * 9 + i] = (uint32_t)vals[2 * i] | ((uint32_t)vals[2 * i + 1] << 16);
        __syncthreads();  // RAW: tile complete
        {
            size_t gb = (size_t)(bh * 64 + fr) * 1152 + cg * 288 + c8 * 36 + fc * 9;
            const uint32_t* Tr = &T32[fr * 37 + fc * 9];
            uint32_t* gp = sb32 + gb;
#pragma unroll
            for (int i = 0; i < 9; ++i) gp[i] = Tr[i];
        }
    }
}

// ================= Kernel 5: GEMM C[320][8192] = Wcat . S^T, 64x64 tiles, bf16 MFMA ==============
__global__ __launch_bounds__(256) void k_wgemm(
    const unsigned short* __restrict__ wcat, const float* __restrict__ bcat,
    const unsigned short* __restrict__ sbuf,
    unsigned short* __restrict__ qb16, unsigned short* __restrict__ kb16,
    unsigned short* __restrict__ vb16)
{
    __shared__ unsigned short Aw[64 * 36];   // rows padded to 36 u16 = 18 words (conflict-free)
    __shared__ unsigned short Bl[64 * 36];

    const int nt = blockIdx.x;  // 0..127 pixel tiles (64 each)
    const int mt = blockIdx.y;  // 0..4 co tiles (64 each)
    const int t = threadIdx.x;
    const int lane = t & 63;
    const int l15 = lane & 15, quad = lane >> 4;
    const int wv = __builtin_amdgcn_readfirstlane(t >> 6);

    const int srow = t >> 2, sch = t & 3;
    const unsigned short* Ag = wcat + (size_t)(mt * 64 + srow) * 2304 + sch * 8;
    const unsigned short* Bg = sbuf + (size_t)(nt * 64 + srow) * 2304 + sch * 8;

    float4v acc[4];
#pragma unroll
    for (int s = 0; s < 4; ++s) acc[s] = (float4v){0.f, 0.f, 0.f, 0.f};

    for (int k0 = 0; k0 < 2304; k0 += 32) {
        uint4 av = *(const uint4*)(Ag + k0);
        uint4 bv = *(const uint4*)(Bg + k0);
        __syncthreads();   // WAR
        *(uint4*)&Aw[srow * 36 + sch * 8] = av;
        *(uint4*)&Bl[srow * 36 + sch * 8] = bv;
        __syncthreads();   // RAW
        short8 afr = *(const short8*)&Aw[(wv * 16 + l15) * 36 + quad * 8];
#pragma unroll
        for (int s = 0; s < 4; ++s) {
            short8 bfr = *(const short8*)&Bl[(s * 16 + l15) * 36 + quad * 8];
            acc[s] = __builtin_amdgcn_mfma_f32_16x16x32_bf16(afr, bfr, acc[s], 0, 0, 0);
        }
    }

    const int cobase = mt * 64 + wv * 16;      // wave-uniform, never crosses q/k/v boundary
    unsigned short* ob; int lco; size_t nper;
    if (cobase < 32)      { ob = qb16; lco = cobase;      nper = (size_t)32 * HW; }
    else if (cobase < 64) { ob = kb16; lco = cobase - 32; nper = (size_t)32 * HW; }
    else                  { ob = vb16; lco = cobase - 64; nper = (size_t)256 * HW; }
    const int b = nt >> 6;
    unsigned short* obb = ob + (size_t)b * nper;
    float bias_r[4];
#pragma unroll
    for (int r = 0; r < 4; ++r) bias_r[r] = bcat[cobase + (quad << 2) + r];
    const int pb = (nt & 63) * 64;
#pragma unroll
    for (int s = 0; s < 4; ++s) {
#pragma unroll
        for (int r = 0; r < 4; ++r) {
            obb[(size_t)(lco + (quad << 2) + r) * HW + pb + s * 16 + l15]
                = f2bf(acc[s][r] + bias_r[r]);
        }
    }
}

// ================= Kernel 6: V transpose: vb16 [j][cc] -> vb16T [cc][j] ==========================
__global__ __launch_bounds__(256) void k_vtrans(
    const unsigned short* __restrict__ vb16, unsigned short* __restrict__ vb16T)
{
    const int jt = blockIdx.x, b = blockIdx.y;
    const int cc = threadIdx.x;
    const unsigned short* src = vb16 + (size_t)b * CHW + (size_t)(jt * 64) * 256 + cc;
    unsigned short* dst = vb16T + (size_t)b * CHW + (size_t)cc * 4096 + jt * 64;
#pragma unroll
    for (int o = 0; o < 8; ++o) {
        union { uint4 v; unsigned short u[8]; } tmp;
#pragma unroll
        for (int j = 0; j < 8; ++j) tmp.u[j] = src[(o * 8 + j) * 256];
        *(uint4*)(dst + o * 8) = tmp.v;
    }
}

// ================= Kernel 7: barrier-free flash attention (bf16 MFMA), cc-split grid =============
// grid (128 q-tiles of 32, 2 cc-halves, B); 512 thr = 8 waves: g = wv>>2 (q16), qu = wv&3 (32 cc).
__global__ __launch_bounds__(512) void k_attn(
    const unsigned short* __restrict__ qb16, const unsigned short* __restrict__ kb16,
    const unsigned short* __restrict__ vb16T, const float* __restrict__ x,
    const float* __restrict__ gamma, float* __restrict__ out)
{
    __shared__ unsigned short pt[8][16 * 40];   // per-wave P buffer (A-layout)

    const int qt = blockIdx.x, ch = blockIdx.y, b = blockIdx.z;
    const int t = threadIdx.x;
    const int lane = t & 63;
    const int wv = t >> 6;
    const int g = wv >> 2, qu = wv & 3;
    const int l15 = lane & 15, quad = lane >> 4;

    const unsigned short* Qb = qb16 + (size_t)b * 32 * HW;
    const unsigned short* Kb = kb16 + (size_t)b * 32 * HW;
    const unsigned short* VT = vb16T + (size_t)b * CHW;

    const int q0 = qt * 32 + g * 16;
    short8 qfr = *(const short8*)(Qb + (size_t)(q0 + l15) * 32 + quad * 8);

    float m_i = -1e30f, l_i = 0.f;
    float4v acc[2];
#pragma unroll
    for (int s = 0; s < 2; ++s) acc[s] = (float4v){0.f, 0.f, 0.f, 0.f};
    unsigned short* ptw = pt[wv];

    for (int jt = 0; jt < 128; ++jt) {
        const int j0 = jt * 32;
        short8 kfr0 = *(const short8*)(Kb + (size_t)(j0 + l15) * 32 + quad * 8);
        short8 kfr1 = *(const short8*)(Kb + (size_t)(j0 + 16 + l15) * 32 + quad * 8);
        float4v s0 = (float4v){0.f, 0.f, 0.f, 0.f}, s1 = s0;
        s0 = __builtin_amdgcn_mfma_f32_16x16x32_bf16(kfr0, qfr, s0, 0, 0, 0);
        s1 = __builtin_amdgcn_mfma_f32_16x16x32_bf16(kfr1, qfr, s1, 0, 0, 0);
        float mx = fmaxf(fmaxf(fmaxf(s0[0], s0[1]), fmaxf(s0[2], s0[3])),
                         fmaxf(fmaxf(s1[0], s1[1]), fmaxf(s1[2], s1[3])));
        mx = fmaxf(mx, __shfl_xor(mx, 16));
        mx = fmaxf(mx, __shfl_xor(mx, 32));
        float mnew = fmaxf(m_i, mx);
        float alpha = __expf(m_i - mnew);
        float p[8]; float ls = 0.f;
#pragma unroll
        for (int r = 0; r < 4; ++r) { p[r] = __expf(s0[r] - mnew); ls += p[r]; }
#pragma unroll
        for (int r = 0; r < 4; ++r) { p[4 + r] = __expf(s1[r] - mnew); ls += p[4 + r]; }
        ls += __shfl_xor(ls, 16);
        ls += __shfl_xor(ls, 32);
        l_i = l_i * alpha + ls;
        m_i = mnew;
        union { uint2 v; unsigned short u[4]; } pk0, pk1;
#pragma unroll
        for (int r = 0; r < 4; ++r) { pk0.u[r] = f2bf(p[r]); pk1.u[r] = f2bf(p[4 + r]); }
        *(uint2*)&ptw[l15 * 40 + quad * 4] = pk0.v;
        *(uint2*)&ptw[l15 * 40 + 16 + quad * 4] = pk1.v;
        float ar[4];
#pragma unroll
        for (int r = 0; r < 4; ++r) ar[r] = __shfl(alpha, (quad << 2) + r);
#pragma unroll
        for (int s = 0; s < 2; ++s) {
            acc[s][0] *= ar[0]; acc[s][1] *= ar[1]; acc[s][2] *= ar[2]; acc[s][3] *= ar[3];
        }
        short8 pfr = *(const short8*)&ptw[l15 * 40 + quad * 8];
#pragma unroll
        for (int s = 0; s < 2; ++s) {
            int cc = ch * 128 + qu * 32 + s * 16 + l15;
            short8 vfr = *(const short8*)(VT + (size_t)cc * 4096 + j0 + quad * 8);
            acc[s] = __builtin_amdgcn_mfma_f32_16x16x32_bf16(pfr, vfr, acc[s], 0, 0, 0);
        }
    }

    float lr[4];
#pragma unroll
    for (int r = 0; r < 4; ++r) lr[r] = __shfl(l_i, (quad << 2) + r);
    const float gm = gamma[0];
    const float* xb = x + (size_t)b * CHW;
    float* ob = out + (size_t)b * CHW;
#pragma unroll
    for (int s = 0; s < 2; ++s) {
#pragma unroll
        for (int r = 0; r < 4; ++r) {
            int q = q0 + (quad << 2) + r;
            int cc = ch * 128 + qu * 32 + s * 16 + l15;
            size_t idx = (size_t)q * 256 + cc;
            ob[idx] = gm * (acc[s][r] / lr[r]) + xb[idx];
        }
    }
}

extern "C" void kernel_launch(void* const* d_in, const int* in_sizes, int n_in,
                              void* d_out, int out_size, void* d_ws, size_t ws_size,
                              hipStream_t stream)
{
    (void)in_sizes; (void)n_in; (void)out_size; (void)ws_size;
    const float* x     = (const float*)d_in[0];
    const float* w_off = (const float*)d_in[1];
    const float* b_off = (const float*)d_in[2];
    const float* wq    = (const float*)d_in[3];
    const float* bq    = (const float*)d_in[4];
    const float* wk    = (const float*)d_in[5];
    const float* bk    = (const float*)d_in[6];
    const float* wv    = (const float*)d_in[7];
    const float* bv    = (const float*)d_in[8];
    const float* gamma = (const float*)d_in[9];
    float* out = (float*)d_out;

    // ws layout (bytes): total ~45.9 MB
    char* ws = (char*)d_ws;
    float*          off_buf = (float*)(ws + 0);                  //   589824
    uint2*          pbw     = (uint2*)(ws + 589824);             //   589824
    uint32_t*       pba     = (uint32_t*)(ws + 1179648);         //   294912
    unsigned short* qb16    = (unsigned short*)(ws + 1474560);   //   524288
    unsigned short* kb16    = (unsigned short*)(ws + 1998848);   //   524288
    unsigned short* vb16T   = (unsigned short*)(ws + 2523136);   //  4194304
    unsigned short* wcat    = (unsigned short*)(ws + 6717440);   //  1474560
    float*          bcat    = (float*)(ws + 8192000);            //     2048
    unsigned short* sbuf    = (unsigned short*)(ws + 8194048);   // 37748736
    // vb16 (natural [co][p] layout) lives in d_out scratch; k_attn later overwrites all of d_out.
    unsigned short* vb16    = (unsigned short*)d_out;

    k_offset_conv<<<dim3(2 * HH), 256, 0, stream>>>(x, w_off, off_buf);
    k_params<<<dim3(2 * HH), 256, 0, stream>>>(off_buf, b_off, pbw, pba);
    k_wcat<<<dim3(720), 256, 0, stream>>>(wq, wk, wv, bq, bk, bv, wcat, bcat);
    k_sample<<<dim3(2 * HH, 4), 256, 0, stream>>>(x, pbw, pba, sbuf);
    k_wgemm<<<dim3(2 * HH, 5), 256, 0, stream>>>(wcat, bcat, sbuf, qb16, kb16, vb16);
    k_vtrans<<<dim3(64, 2), 256, 0, stream>>>(vb16, vb16T);
    k_attn<<<dim3(128, 2, 2), 512, 0, stream>>>(qb16, kb16, vb16T, x, gamma, out);
}

// Round 7
// 424.674 us; speedup vs baseline: 5.9528x; 1.0398x over previous
//
#include <hip/hip_runtime.h>
#include <math.h>
#include <stdint.h>

#define CIN 256
#define HH 64
#define WW 64
#define HW 4096
#define CHW (CIN * HW) // 1048576

typedef __attribute__((ext_vector_type(8))) short short8;   // 8 bf16 = 4 VGPR (MFMA A/B frag)
typedef __attribute__((ext_vector_type(4))) float float4v;  // MFMA C/D frag
typedef __attribute__((ext_vector_type(2))) float f2a;

__device__ inline unsigned short f2bf(float f) {
    union { float f; uint32_t u; } v; v.f = f;
    return (unsigned short)((v.u + 0x7FFFu + ((v.u >> 16) & 1u)) >> 16);
}
__device__ inline float bf2f(unsigned short h) {
    union { uint32_t u; float f; } v; v.u = ((uint32_t)h) << 16;
    return v.f;
}
__device__ inline f2a ldg2(const float* p) {
    f2a r; __builtin_memcpy(&r, p, 8); return r;
}

// ================= Kernel 1: offset = conv3x3(x, w_off) (fp32) — R3-proven =======================
__global__ __launch_bounds__(256) void k_offset_conv(
    const float* __restrict__ x, const float* __restrict__ w_off,
    float* __restrict__ off_out)
{
    __shared__ float red[4][64][18];
    const int blk = blockIdx.x;
    const int b = blk >> 6, h = blk & 63;
    const int t = threadIdx.x;
    const int w = t & 63;
    const int wv = __builtin_amdgcn_readfirstlane(t >> 6);
    float acc[18];
#pragma unroll
    for (int i = 0; i < 18; ++i) acc[i] = 0.f;
    const float* xb = x + (size_t)b * CHW;
    for (int ci = 0; ci < 64; ++ci) {
        const int c = wv * 64 + ci;
        const float* xc = xb + (size_t)c * HW;
        float r0 = (h > 0)  ? xc[(h - 1) * WW + w] : 0.f;
        float r1 =            xc[h * WW + w];
        float r2 = (h < 63) ? xc[(h + 1) * WW + w] : 0.f;
        float l0 = __shfl_up(r0, 1), l1 = __shfl_up(r1, 1), l2 = __shfl_up(r2, 1);
        float d0 = __shfl_down(r0, 1), d1 = __shfl_down(r1, 1), d2 = __shfl_down(r2, 1);
        if (w == 0)  { l0 = 0.f; l1 = 0.f; l2 = 0.f; }
        if (w == 63) { d0 = 0.f; d1 = 0.f; d2 = 0.f; }
        const float xv[9] = {l0, r0, d0, l1, r1, d1, l2, r2, d2};
        const float* wc = w_off + (size_t)c * 9;
#pragma unroll
        for (int co = 0; co < 18; ++co) {
            const float* wp = wc + (size_t)co * (CIN * 9);
#pragma unroll
            for (int k = 0; k < 9; ++k) acc[co] += wp[k] * xv[k];
        }
    }
#pragma unroll
    for (int co = 0; co < 18; ++co) red[wv][w][co] = acc[co];
    __syncthreads();
    if (t < 64) {
#pragma unroll
        for (int co = 0; co < 18; ++co) {
            float s = red[0][t][co] + red[1][t][co] + red[2][t][co] + red[3][t][co];
            off_out[((b * 18 + co) * HH + h) * WW + t] = s;
        }
    }
}

// ================= Kernel 2: patch-form bilinear params — R3-proven ==============================
__global__ __launch_bounds__(256) void k_params(
    const float* __restrict__ off_buf, const float* __restrict__ b_off,
    uint2* __restrict__ pbw, uint32_t* __restrict__ pba)
{
    const int bh = blockIdx.x;
    const int b = bh >> 6, h = bh & 63;
    const int t = threadIdx.x;
    for (int r = 0; r < 3; ++r) {
        int sid = t + 256 * r;
        if (sid < 576) {
            int k = sid >> 6, ww = sid & 63;
            float dy = off_buf[((b * 18 + 2 * k) * HH + h) * WW + ww] + b_off[2 * k];
            float dx = off_buf[((b * 18 + 2 * k + 1) * HH + h) * WW + ww] + b_off[2 * k + 1];
            float py = (float)(h + k / 3 - 1) + dy;
            float px = (float)(ww + k % 3 - 1) + dx;
            float y0f = floorf(py), x0f = floorf(px);
            float fy = py - y0f, fx = px - x0f;
            int y0 = (int)y0f, x0 = (int)x0f;
            int yb = min(max(y0, 0), 62), xb = min(max(x0, 0), 62);
            float wr[2] = {0.f, 0.f}, wc[2] = {0.f, 0.f};
            if (y0 >= 0 && y0 < HH) wr[y0 - yb] += 1.f - fy;
            if (y0 + 1 >= 0 && y0 + 1 < HH) wr[y0 + 1 - yb] += fy;
            if (x0 >= 0 && x0 < WW) wc[x0 - xb] += 1.f - fx;
            if (x0 + 1 >= 0 && x0 + 1 < WW) wc[x0 + 1 - xb] += fx;
            uint2 pw;
            pw.x = (uint32_t)f2bf(wr[0] * wc[0]) | ((uint32_t)f2bf(wr[0] * wc[1]) << 16);
            pw.y = (uint32_t)f2bf(wr[1] * wc[0]) | ((uint32_t)f2bf(wr[1] * wc[1]) << 16);
            pbw[(size_t)bh * 576 + sid] = pw;
            pba[(size_t)bh * 576 + sid] = (uint32_t)(yb * WW + xb);
        }
    }
}

// ================= Kernel 3: W concat + bf16 cast — R3-proven ====================================
__global__ __launch_bounds__(256) void k_wcat(
    const float* __restrict__ wq, const float* __restrict__ wk, const float* __restrict__ wv_,
    const float* __restrict__ bq, const float* __restrict__ bk, const float* __restrict__ bv,
    unsigned short* __restrict__ wcat, float* __restrict__ bcat)
{
    int e = (blockIdx.x * 256 + threadIdx.x) * 4;
    const float* src;
    if (e < 32 * 2304)      src = wq + e;
    else if (e < 64 * 2304) src = wk + (e - 32 * 2304);
    else                    src = wv_ + (e - 64 * 2304);
    float4 v = *(const float4*)src;
    unsigned short o[4] = {f2bf(v.x), f2bf(v.y), f2bf(v.z), f2bf(v.w)};
    *(uint2*)(wcat + e) = *(const uint2*)o;
    if (blockIdx.x == 0 && threadIdx.x < 320) {
        int c = threadIdx.x;
        bcat[c] = c < 32 ? bq[c] : (c < 64 ? bk[c - 32] : bv[c - 64]);
    }
}

// ================= Kernel 4: sample S[n=8192][k=2304] bf16 — R3-proven ===========================
__global__ __launch_bounds__(256) void k_sample(
    const float* __restrict__ x, const uint2* __restrict__ pbw,
    const uint32_t* __restrict__ pba, unsigned short* __restrict__ sbuf)
{
    __shared__ uint2 prw[576];
    __shared__ uint32_t pra[576];
    __shared__ uint32_t T32[64 * 37];

    const int bh = blockIdx.x;
    const int cg = blockIdx.y;
    const int b = bh >> 6;
    const int t = threadIdx.x;
    const int p = t & 63;
    const int duo = t >> 6;

    for (int r = 0; r < 3; ++r) {
        int sid = t + 256 * r;
        if (sid < 576) { prw[sid] = pbw[(size_t)bh * 576 + sid]; pra[sid] = pba[(size_t)bh * 576 + sid]; }
    }
    __syncthreads();

    const float* xb = x + (size_t)b * CHW;
    const int fr = t >> 2, fc = t & 3;
    uint32_t* sb32 = (uint32_t*)sbuf;

    for (int c8 = 0; c8 < 8; ++c8) {
        const int ca = cg * 64 + c8 * 8 + duo * 2;
        const float* xpa = xb + (size_t)ca * HW;
        const float* xpb = xpa + HW;
        unsigned short vals[18];
#pragma unroll
        for (int tap = 0; tap < 9; ++tap) {
            uint2 wv2 = prw[tap * 64 + p];
            uint32_t base = pra[tap * 64 + p];
            float w00 = bf2f((unsigned short)(wv2.x & 0xFFFF));
            float w01 = bf2f((unsigned short)(wv2.x >> 16));
            float w10 = bf2f((unsigned short)(wv2.y & 0xFFFF));
            float w11 = bf2f((unsigned short)(wv2.y >> 16));
            f2a a0 = ldg2(xpa + base), a1 = ldg2(xpa + base + WW);
            f2a b0 = ldg2(xpb + base), b1 = ldg2(xpb + base + WW);
            vals[tap]     = f2bf(w00 * a0.x + w01 * a0.y + w10 * a1.x + w11 * a1.y);
            vals[9 + tap] = f2bf(w00 * b0.x + w01 * b0.y + w10 * b1.x + w11 * b1.y);
        }
        __syncthreads();
#pragma unroll
        for (int i = 0; i < 9; ++i)
            T32[p * 37 + duo * 9 + i] = (uint32_t)vals[2 * i] | ((uint32_t)vals[2 * i + 1] << 16);
        __syncthreads();
        {
            size_t gb = (size_t)(bh * 64 + fr) * 1152 + cg * 288 + c8 * 36 + fc * 9;
            const uint32_t* Tr = &T32[fr * 37 + fc * 9];
            uint32_t* gp = sb32 + gb;
#pragma unroll
            for (int i = 0; i < 9; ++i) gp[i] = Tr[i];
        }
    }
}

// ================= Kernel 5: GEMM C[320][8192] = Wcat . S^T — R3-proven ==========================
// qb16/kb16: [32 c][4096 p] flat; vb16: [256 c][4096 p] flat. The reference's .reshape() is a RAW
// REINTERPRET of these flats: Q_attn[i][d] = qb16[i*32+d], V_attn[j][cc] = vb16[j*256+cc].
__global__ __launch_bounds__(256) void k_wgemm(
    const unsigned short* __restrict__ wcat, const float* __restrict__ bcat,
    const unsigned short* __restrict__ sbuf,
    unsigned short* __restrict__ qb16, unsigned short* __restrict__ kb16,
    unsigned short* __restrict__ vb16)
{
    __shared__ unsigned short Aw[64 * 36];
    __shared__ unsigned short Bl[64 * 36];

    const int nt = blockIdx.x;
    const int mt = blockIdx.y;
    const int t = threadIdx.x;
    const int lane = t & 63;
    const int l15 = lane & 15, quad = lane >> 4;
    const int wv = __builtin_amdgcn_readfirstlane(t >> 6);

    const int srow = t >> 2, sch = t & 3;
    const unsigned short* Ag = wcat + (size_t)(mt * 64 + srow) * 2304 + sch * 8;
    const unsigned short* Bg = sbuf + (size_t)(nt * 64 + srow) * 2304 + sch * 8;

    float4v acc[4];
#pragma unroll
    for (int s = 0; s < 4; ++s) acc[s] = (float4v){0.f, 0.f, 0.f, 0.f};

    for (int k0 = 0; k0 < 2304; k0 += 32) {
        uint4 av = *(const uint4*)(Ag + k0);
        uint4 bv = *(const uint4*)(Bg + k0);
        __syncthreads();
        *(uint4*)&Aw[srow * 36 + sch * 8] = av;
        *(uint4*)&Bl[srow * 36 + sch * 8] = bv;
        __syncthreads();
        short8 afr = *(const short8*)&Aw[(wv * 16 + l15) * 36 + quad * 8];
#pragma unroll
        for (int s = 0; s < 4; ++s) {
            short8 bfr = *(const short8*)&Bl[(s * 16 + l15) * 36 + quad * 8];
            acc[s] = __builtin_amdgcn_mfma_f32_16x16x32_bf16(afr, bfr, acc[s], 0, 0, 0);
        }
    }

    const int cobase = mt * 64 + wv * 16;
    unsigned short* ob; int lco; size_t nper;
    if (cobase < 32)      { ob = qb16; lco = cobase;      nper = (size_t)32 * HW; }
    else if (cobase < 64) { ob = kb16; lco = cobase - 32; nper = (size_t)32 * HW; }
    else                  { ob = vb16; lco = cobase - 64; nper = (size_t)256 * HW; }
    const int b = nt >> 6;
    unsigned short* obb = ob + (size_t)b * nper;
    float bias_r[4];
#pragma unroll
    for (int r = 0; r < 4; ++r) bias_r[r] = bcat[cobase + (quad << 2) + r];
    const int pb = (nt & 63) * 64;
#pragma unroll
    for (int s = 0; s < 4; ++s) {
#pragma unroll
        for (int r = 0; r < 4; ++r) {
            obb[(size_t)(lco + (quad << 2) + r) * HW + pb + s * 16 + l15]
                = f2bf(acc[s][r] + bias_r[r]);
        }
    }
}

// ================= Kernel 6: V re-layout — R2/R3-proven ==========================================
// Reads vb16 flat AS the reinterpreted V_attn[j][cc] (= vb16[j*256+cc]) and writes VT2[cc][j],
// which is the B-frag layout for PV (k = j contiguous per cc).
__global__ __launch_bounds__(256) void k_vtrans(
    const unsigned short* __restrict__ vb16, unsigned short* __restrict__ vb16T)
{
    const int jt = blockIdx.x, b = blockIdx.y;
    const int cc = threadIdx.x;
    const unsigned short* src = vb16 + (size_t)b * CHW + (size_t)(jt * 64) * 256 + cc;
    unsigned short* dst = vb16T + (size_t)b * CHW + (size_t)cc * 4096 + jt * 64;
#pragma unroll
    for (int o = 0; o < 8; ++o) {
        union { uint4 v; unsigned short u[8]; } tmp;
#pragma unroll
        for (int j = 0; j < 8; ++j) tmp.u[j] = src[(o * 8 + j) * 256];
        *(uint4*)(dst + o * 8) = tmp.v;
    }
}

// ================= Kernel 7: flash attention, max-free softmax, shuffle-free loop ================
// grid (128 qt of 32 q, 2 ch of 128 cc, B); 256 thr = 4 waves: g = wv&1 (16 q), jh = wv>>1.
// Q/K read directly from the FLAT conv buffers: Q_attn[i][d] = qb16[i*32+d] (raw reshape).
#define SM_SHIFT 16.0f
__global__ __launch_bounds__(256) void k_attn(
    const unsigned short* __restrict__ qb16, const unsigned short* __restrict__ kb16,
    const unsigned short* __restrict__ vt, const float* __restrict__ x,
    const float* __restrict__ gamma, float* __restrict__ out)
{
    __shared__ unsigned short ptl[4][16 * 40];
    __shared__ float red[2][64][36];

    const int qt = blockIdx.x, ch = blockIdx.y, b = blockIdx.z;
    const int t = threadIdx.x;
    const int lane = t & 63;
    const int wv = t >> 6;
    const int g = wv & 1, jh = wv >> 1;
    const int l15 = lane & 15, quad = lane >> 4;

    const unsigned short* Qb = qb16 + (size_t)b * (32 * 4096);
    const unsigned short* Kb = kb16 + (size_t)b * (32 * 4096);
    const unsigned short* VT = vt + (size_t)b * CHW;

    const int q0 = qt * 32 + g * 16;
    short8 qfr = *(const short8*)(Qb + (size_t)(q0 + l15) * 32 + quad * 8);

    float l_i = 0.f;
    float4v acc[8];
#pragma unroll
    for (int s = 0; s < 8; ++s) acc[s] = (float4v){0.f, 0.f, 0.f, 0.f};
    unsigned short* pw = ptl[wv];
    const int jbase = jh * 2048;

    for (int jt = 0; jt < 64; ++jt) {
        const int j0 = jbase + jt * 32;
        short8 kfr0 = *(const short8*)(Kb + (size_t)(j0 + l15) * 32 + quad * 8);
        short8 kfr1 = *(const short8*)(Kb + (size_t)(j0 + 16 + l15) * 32 + quad * 8);
        float4v s0 = (float4v){0.f, 0.f, 0.f, 0.f}, s1 = s0;
        s0 = __builtin_amdgcn_mfma_f32_16x16x32_bf16(kfr0, qfr, s0, 0, 0, 0);
        s1 = __builtin_amdgcn_mfma_f32_16x16x32_bf16(kfr1, qfr, s1, 0, 0, 0);
        // D: row = j (quad*4+r), col = q (l15). p = exp(s - SHIFT): scores bounded, max-free.
        float p[8]; float ls = 0.f;
#pragma unroll
        for (int r = 0; r < 4; ++r) { p[r] = __expf(s0[r] - SM_SHIFT); ls += p[r]; }
#pragma unroll
        for (int r = 0; r < 4; ++r) { p[4 + r] = __expf(s1[r] - SM_SHIFT); ls += p[4 + r]; }
        l_i += ls;
        union { uint2 v; unsigned short u[4]; } pk0, pk1;
#pragma unroll
        for (int r = 0; r < 4; ++r) { pk0.u[r] = f2bf(p[r]); pk1.u[r] = f2bf(p[4 + r]); }
        *(uint2*)&pw[l15 * 40 + (quad << 2)] = pk0.v;        // P[q=l15][j_local=quad*4+r]
        *(uint2*)&pw[l15 * 40 + 16 + (quad << 2)] = pk1.v;   // P[q=l15][16+quad*4+r]
        short8 pfr = *(const short8*)&pw[l15 * 40 + quad * 8];  // A[m=q][k=j] (wave-private)
#pragma unroll
        for (int s = 0; s < 8; ++s) {
            int cc = ch * 128 + s * 16 + l15;
            short8 vfr = *(const short8*)(VT + (size_t)cc * 4096 + j0 + quad * 8);
            acc[s] = __builtin_amdgcn_mfma_f32_16x16x32_bf16(pfr, vfr, acc[s], 0, 0, 0);
        }
    }

    l_i += __shfl_xor(l_i, 16);
    l_i += __shfl_xor(l_i, 32);

    __syncthreads();
    if (jh == 1) {
#pragma unroll
        for (int s = 0; s < 8; ++s) *(float4v*)&red[g][lane][s * 4] = acc[s];
        red[g][lane][32] = l_i;
    }
    __syncthreads();
    if (jh == 0) {
#pragma unroll
        for (int s = 0; s < 8; ++s) {
            float4v o = *(const float4v*)&red[g][lane][s * 4];
            acc[s][0] += o[0]; acc[s][1] += o[1]; acc[s][2] += o[2]; acc[s][3] += o[3];
        }
        l_i += red[g][lane][32];
        float lr[4];
#pragma unroll
        for (int r = 0; r < 4; ++r) lr[r] = __shfl(l_i, (quad << 2) + r);
        const float gm = gamma[0];
        const float* xb = x + (size_t)b * CHW;
        float* ob = out + (size_t)b * CHW;
#pragma unroll
        for (int s = 0; s < 8; ++s) {
#pragma unroll
            for (int r = 0; r < 4; ++r) {
                int q = q0 + (quad << 2) + r;
                int cc = ch * 128 + s * 16 + l15;
                size_t idx = (size_t)q * 256 + cc;
                ob[idx] = gm * (acc[s][r] / lr[r]) + xb[idx];
            }
        }
    }
}

extern "C" void kernel_launch(void* const* d_in, const int* in_sizes, int n_in,
                              void* d_out, int out_size, void* d_ws, size_t ws_size,
                              hipStream_t stream)
{
    (void)in_sizes; (void)n_in; (void)out_size; (void)ws_size;
    const float* x     = (const float*)d_in[0];
    const float* w_off = (const float*)d_in[1];
    const float* b_off = (const float*)d_in[2];
    const float* wq    = (const float*)d_in[3];
    const float* bq    = (const float*)d_in[4];
    const float* wk    = (const float*)d_in[5];
    const float* bk    = (const float*)d_in[6];
    const float* wv    = (const float*)d_in[7];
    const float* bv    = (const float*)d_in[8];
    const float* gamma = (const float*)d_in[9];
    float* out = (float*)d_out;

    // ws layout (bytes): total 45,942,784 — R3's exact proven footprint.
    char* ws = (char*)d_ws;
    float*          off_buf = (float*)(ws + 0);                  //  589824
    uint2*          pbw     = (uint2*)(ws + 589824);             //  589824
    uint32_t*       pba     = (uint32_t*)(ws + 1179648);         //  294912
    unsigned short* qb16    = (unsigned short*)(ws + 1474560);   //  524288 [32 c][4096 p] flat
    unsigned short* kb16    = (unsigned short*)(ws + 1998848);   //  524288 [32 c][4096 p] flat
    unsigned short* vb16T   = (unsigned short*)(ws + 2523136);   // 4194304 VT2[cc][j]
    unsigned short* wcat    = (unsigned short*)(ws + 6717440);   // 1474560
    float*          bcat    = (float*)(ws + 8192000);            //    2048
    unsigned short* sbuf    = (unsigned short*)(ws + 8194048);   // 37748736
    // vb16 ([256 c][4096 p] flat) lives in d_out scratch; k_attn later overwrites all of d_out.
    unsigned short* vb16    = (unsigned short*)d_out;

    k_offset_conv<<<dim3(2 * HH), 256, 0, stream>>>(x, w_off, off_buf);
    k_params<<<dim3(2 * HH), 256, 0, stream>>>(off_buf, b_off, pbw, pba);
    k_wcat<<<dim3(720), 256, 0, stream>>>(wq, wk, wv, bq, bk, bv, wcat, bcat);
    k_sample<<<dim3(2 * HH, 4), 256, 0, stream>>>(x, pbw, pba, sbuf);
    k_wgemm<<<dim3(2 * HH, 5), 256, 0, stream>>>(wcat, bcat, sbuf, qb16, kb16, vb16);
    k_vtrans<<<dim3(64, 2), 256, 0, stream>>>(vb16, vb16T);
    k_attn<<<dim3(128, 2, 2), 256, 0, stream>>>(qb16, kb16, vb16T, x, gamma, out);
}

// Round 8
// 331.475 us; speedup vs baseline: 7.6265x; 1.2812x over previous
//
#include <hip/hip_runtime.h>
#include <math.h>
#include <stdint.h>

#define CIN 256
#define HH 64
#define WW 64
#define HW 4096
#define CHW (CIN * HW) // 1048576

typedef __attribute__((ext_vector_type(8))) short short8;   // 8 bf16 = 4 VGPR (MFMA A/B frag)
typedef __attribute__((ext_vector_type(4))) float float4v;  // MFMA C/D frag
typedef __attribute__((ext_vector_type(2))) float f2a;

__device__ inline unsigned short f2bf(float f) {
    union { float f; uint32_t u; } v; v.f = f;
    return (unsigned short)((v.u + 0x7FFFu + ((v.u >> 16) & 1u)) >> 16);
}
__device__ inline float bf2f(unsigned short h) {
    union { uint32_t u; float f; } v; v.u = ((uint32_t)h) << 16;
    return v.f;
}
__device__ inline f2a ldg2(const float* p) {
    f2a r; __builtin_memcpy(&r, p, 8); return r;
}

// ================= Kernel 1: offset = conv3x3(x, w_off) (fp32) — R3/R7-proven ====================
__global__ __launch_bounds__(256) void k_offset_conv(
    const float* __restrict__ x, const float* __restrict__ w_off,
    float* __restrict__ off_out)
{
    __shared__ float red[4][64][18];
    const int blk = blockIdx.x;
    const int b = blk >> 6, h = blk & 63;
    const int t = threadIdx.x;
    const int w = t & 63;
    const int wv = __builtin_amdgcn_readfirstlane(t >> 6);
    float acc[18];
#pragma unroll
    for (int i = 0; i < 18; ++i) acc[i] = 0.f;
    const float* xb = x + (size_t)b * CHW;
    for (int ci = 0; ci < 64; ++ci) {
        const int c = wv * 64 + ci;
        const float* xc = xb + (size_t)c * HW;
        float r0 = (h > 0)  ? xc[(h - 1) * WW + w] : 0.f;
        float r1 =            xc[h * WW + w];
        float r2 = (h < 63) ? xc[(h + 1) * WW + w] : 0.f;
        float l0 = __shfl_up(r0, 1), l1 = __shfl_up(r1, 1), l2 = __shfl_up(r2, 1);
        float d0 = __shfl_down(r0, 1), d1 = __shfl_down(r1, 1), d2 = __shfl_down(r2, 1);
        if (w == 0)  { l0 = 0.f; l1 = 0.f; l2 = 0.f; }
        if (w == 63) { d0 = 0.f; d1 = 0.f; d2 = 0.f; }
        const float xv[9] = {l0, r0, d0, l1, r1, d1, l2, r2, d2};
        const float* wc = w_off + (size_t)c * 9;
#pragma unroll
        for (int co = 0; co < 18; ++co) {
            const float* wp = wc + (size_t)co * (CIN * 9);
#pragma unroll
            for (int k = 0; k < 9; ++k) acc[co] += wp[k] * xv[k];
        }
    }
#pragma unroll
    for (int co = 0; co < 18; ++co) red[wv][w][co] = acc[co];
    __syncthreads();
    if (t < 64) {
#pragma unroll
        for (int co = 0; co < 18; ++co) {
            float s = red[0][t][co] + red[1][t][co] + red[2][t][co] + red[3][t][co];
            off_out[((b * 18 + co) * HH + h) * WW + t] = s;
        }
    }
}

// ================= Kernel 2: patch-form bilinear params — R3/R7-proven ===========================
__global__ __launch_bounds__(256) void k_params(
    const float* __restrict__ off_buf, const float* __restrict__ b_off,
    uint2* __restrict__ pbw, uint32_t* __restrict__ pba)
{
    const int bh = blockIdx.x;
    const int b = bh >> 6, h = bh & 63;
    const int t = threadIdx.x;
    for (int r = 0; r < 3; ++r) {
        int sid = t + 256 * r;
        if (sid < 576) {
            int k = sid >> 6, ww = sid & 63;
            float dy = off_buf[((b * 18 + 2 * k) * HH + h) * WW + ww] + b_off[2 * k];
            float dx = off_buf[((b * 18 + 2 * k + 1) * HH + h) * WW + ww] + b_off[2 * k + 1];
            float py = (float)(h + k / 3 - 1) + dy;
            float px = (float)(ww + k % 3 - 1) + dx;
            float y0f = floorf(py), x0f = floorf(px);
            float fy = py - y0f, fx = px - x0f;
            int y0 = (int)y0f, x0 = (int)x0f;
            int yb = min(max(y0, 0), 62), xb = min(max(x0, 0), 62);
            float wr[2] = {0.f, 0.f}, wc[2] = {0.f, 0.f};
            if (y0 >= 0 && y0 < HH) wr[y0 - yb] += 1.f - fy;
            if (y0 + 1 >= 0 && y0 + 1 < HH) wr[y0 + 1 - yb] += fy;
            if (x0 >= 0 && x0 < WW) wc[x0 - xb] += 1.f - fx;
            if (x0 + 1 >= 0 && x0 + 1 < WW) wc[x0 + 1 - xb] += fx;
            uint2 pw;
            pw.x = (uint32_t)f2bf(wr[0] * wc[0]) | ((uint32_t)f2bf(wr[0] * wc[1]) << 16);
            pw.y = (uint32_t)f2bf(wr[1] * wc[0]) | ((uint32_t)f2bf(wr[1] * wc[1]) << 16);
            pbw[(size_t)bh * 576 + sid] = pw;
            pba[(size_t)bh * 576 + sid] = (uint32_t)(yb * WW + xb);
        }
    }
}

// ================= Kernel 3: W concat + bf16 cast — R3/R7-proven =================================
__global__ __launch_bounds__(256) void k_wcat(
    const float* __restrict__ wq, const float* __restrict__ wk, const float* __restrict__ wv_,
    const float* __restrict__ bq, const float* __restrict__ bk, const float* __restrict__ bv,
    unsigned short* __restrict__ wcat, float* __restrict__ bcat)
{
    int e = (blockIdx.x * 256 + threadIdx.x) * 4;
    const float* src;
    if (e < 32 * 2304)      src = wq + e;
    else if (e < 64 * 2304) src = wk + (e - 32 * 2304);
    else                    src = wv_ + (e - 64 * 2304);
    float4 v = *(const float4*)src;
    unsigned short o[4] = {f2bf(v.x), f2bf(v.y), f2bf(v.z), f2bf(v.w)};
    *(uint2*)(wcat + e) = *(const uint2*)o;
    if (blockIdx.x == 0 && threadIdx.x < 320) {
        int c = threadIdx.x;
        bcat[c] = c < 32 ? bq[c] : (c < 64 ? bk[c - 32] : bv[c - 64]);
    }
}

// ================= Kernel 4: sample S[n=8192][k=2304] bf16 — R3/R7-proven ========================
__global__ __launch_bounds__(256) void k_sample(
    const float* __restrict__ x, const uint2* __restrict__ pbw,
    const uint32_t* __restrict__ pba, unsigned short* __restrict__ sbuf)
{
    __shared__ uint2 prw[576];
    __shared__ uint32_t pra[576];
    __shared__ uint32_t T32[64 * 37];

    const int bh = blockIdx.x;
    const int cg = blockIdx.y;
    const int b = bh >> 6;
    const int t = threadIdx.x;
    const int p = t & 63;
    const int duo = t >> 6;

    for (int r = 0; r < 3; ++r) {
        int sid = t + 256 * r;
        if (sid < 576) { prw[sid] = pbw[(size_t)bh * 576 + sid]; pra[sid] = pba[(size_t)bh * 576 + sid]; }
    }
    __syncthreads();

    const float* xb = x + (size_t)b * CHW;
    const int fr = t >> 2, fc = t & 3;
    uint32_t* sb32 = (uint32_t*)sbuf;

    for (int c8 = 0; c8 < 8; ++c8) {
        const int ca = cg * 64 + c8 * 8 + duo * 2;
        const float* xpa = xb + (size_t)ca * HW;
        const float* xpb = xpa + HW;
        unsigned short vals[18];
#pragma unroll
        for (int tap = 0; tap < 9; ++tap) {
            uint2 wv2 = prw[tap * 64 + p];
            uint32_t base = pra[tap * 64 + p];
            float w00 = bf2f((unsigned short)(wv2.x & 0xFFFF));
            float w01 = bf2f((unsigned short)(wv2.x >> 16));
            float w10 = bf2f((unsigned short)(wv2.y & 0xFFFF));
            float w11 = bf2f((unsigned short)(wv2.y >> 16));
            f2a a0 = ldg2(xpa + base), a1 = ldg2(xpa + base + WW);
            f2a b0 = ldg2(xpb + base), b1 = ldg2(xpb + base + WW);
            vals[tap]     = f2bf(w00 * a0.x + w01 * a0.y + w10 * a1.x + w11 * a1.y);
            vals[9 + tap] = f2bf(w00 * b0.x + w01 * b0.y + w10 * b1.x + w11 * b1.y);
        }
        __syncthreads();
#pragma unroll
        for (int i = 0; i < 9; ++i)
            T32[p * 37 + duo * 9 + i] = (uint32_t)vals[2 * i] | ((uint32_t)vals[2 * i + 1] << 16);
        __syncthreads();
        {
            size_t gb = (size_t)(bh * 64 + fr) * 1152 + cg * 288 + c8 * 36 + fc * 9;
            const uint32_t* Tr = &T32[fr * 37 + fc * 9];
            uint32_t* gp = sb32 + gb;
#pragma unroll
            for (int i = 0; i < 9; ++i) gp[i] = Tr[i];
        }
    }
}

// ================= Kernel 5: GEMM C[320][8192] = Wcat . S^T — R3/R7-proven =======================
__global__ __launch_bounds__(256) void k_wgemm(
    const unsigned short* __restrict__ wcat, const float* __restrict__ bcat,
    const unsigned short* __restrict__ sbuf,
    unsigned short* __restrict__ qb16, unsigned short* __restrict__ kb16,
    unsigned short* __restrict__ vb16)
{
    __shared__ unsigned short Aw[64 * 36];
    __shared__ unsigned short Bl[64 * 36];

    const int nt = blockIdx.x;
    const int mt = blockIdx.y;
    const int t = threadIdx.x;
    const int lane = t & 63;
    const int l15 = lane & 15, quad = lane >> 4;
    const int wv = __builtin_amdgcn_readfirstlane(t >> 6);

    const int srow = t >> 2, sch = t & 3;
    const unsigned short* Ag = wcat + (size_t)(mt * 64 + srow) * 2304 + sch * 8;
    const unsigned short* Bg = sbuf + (size_t)(nt * 64 + srow) * 2304 + sch * 8;

    float4v acc[4];
#pragma unroll
    for (int s = 0; s < 4; ++s) acc[s] = (float4v){0.f, 0.f, 0.f, 0.f};

    for (int k0 = 0; k0 < 2304; k0 += 32) {
        uint4 av = *(const uint4*)(Ag + k0);
        uint4 bv = *(const uint4*)(Bg + k0);
        __syncthreads();
        *(uint4*)&Aw[srow * 36 + sch * 8] = av;
        *(uint4*)&Bl[srow * 36 + sch * 8] = bv;
        __syncthreads();
        short8 afr = *(const short8*)&Aw[(wv * 16 + l15) * 36 + quad * 8];
#pragma unroll
        for (int s = 0; s < 4; ++s) {
            short8 bfr = *(const short8*)&Bl[(s * 16 + l15) * 36 + quad * 8];
            acc[s] = __builtin_amdgcn_mfma_f32_16x16x32_bf16(afr, bfr, acc[s], 0, 0, 0);
        }
    }

    const int cobase = mt * 64 + wv * 16;
    unsigned short* ob; int lco; size_t nper;
    if (cobase < 32)      { ob = qb16; lco = cobase;      nper = (size_t)32 * HW; }
    else if (cobase < 64) { ob = kb16; lco = cobase - 32; nper = (size_t)32 * HW; }
    else                  { ob = vb16; lco = cobase - 64; nper = (size_t)256 * HW; }
    const int b = nt >> 6;
    unsigned short* obb = ob + (size_t)b * nper;
    float bias_r[4];
#pragma unroll
    for (int r = 0; r < 4; ++r) bias_r[r] = bcat[cobase + (quad << 2) + r];
    const int pb = (nt & 63) * 64;
#pragma unroll
    for (int s = 0; s < 4; ++s) {
#pragma unroll
        for (int r = 0; r < 4; ++r) {
            obb[(size_t)(lco + (quad << 2) + r) * HW + pb + s * 16 + l15]
                = f2bf(acc[s][r] + bias_r[r]);
        }
    }
}

// ================= Kernel 6: V re-layout — R2/R3/R7-proven =======================================
__global__ __launch_bounds__(256) void k_vtrans(
    const unsigned short* __restrict__ vb16, unsigned short* __restrict__ vb16T)
{
    const int jt = blockIdx.x, b = blockIdx.y;
    const int cc = threadIdx.x;
    const unsigned short* src = vb16 + (size_t)b * CHW + (size_t)(jt * 64) * 256 + cc;
    unsigned short* dst = vb16T + (size_t)b * CHW + (size_t)cc * 4096 + jt * 64;
#pragma unroll
    for (int o = 0; o < 8; ++o) {
        union { uint4 v; unsigned short u[8]; } tmp;
#pragma unroll
        for (int j = 0; j < 8; ++j) tmp.u[j] = src[(o * 8 + j) * 256];
        *(uint4*)(dst + o * 8) = tmp.v;
    }
}

// ================= Kernel 7: flash attention with LDS-staged K/V tiles ===========================
// grid (128 qt of 32 q, 4 ch of 64 cc, B) = 1024 blocks; 256 thr = 4 waves:
// g = wv&1 (16 q), jh = wv>>1 (j-half of 2048, 64 rounds of 32 j).
// Per round the block cooperatively stages, coalesced: Vt[jh][64 cc][32 j] and Kt[jh][32 j][32 d].
#define SM_SHIFT 16.0f
__global__ __launch_bounds__(256) void k_attn(
    const unsigned short* __restrict__ qb16, const unsigned short* __restrict__ kb16,
    const unsigned short* __restrict__ vt, const float* __restrict__ x,
    const float* __restrict__ gamma, float* __restrict__ out)
{
    __shared__ unsigned short ptl[4][16 * 40];   // per-wave P buffer (A-layout), 5120 B
    __shared__ unsigned short Vt[2][64][40];     // V^T tiles, rows padded to 80 B, 10240 B
    __shared__ unsigned short Kt[2][32][36];     // K tiles, rows padded to 72 B, 4608 B
    __shared__ float red[2][64][20];             // jh=1 partials: 4x float4 + l, 10240 B

    const int qt = blockIdx.x, ch = blockIdx.y, b = blockIdx.z;
    const int t = threadIdx.x;
    const int lane = t & 63;
    const int wv = t >> 6;
    const int g = wv & 1, jh = wv >> 1;
    const int l15 = lane & 15, quad = lane >> 4;
    const int cc0 = ch * 64;

    const unsigned short* Qb = qb16 + (size_t)b * (32 * 4096);
    const unsigned short* Kb = kb16 + (size_t)b * (32 * 4096);
    const unsigned short* VT = vt + (size_t)b * CHW;

    const int q0 = qt * 32 + g * 16;
    short8 qfr = *(const short8*)(Qb + (size_t)(q0 + l15) * 32 + quad * 8);   // Q[q][d] flat

    // staging maps (wave-uniform shapes)
    const int vcc = t >> 2, voff = (t & 3) * 8;          // V: 4 thr/row, 64 rows
    const int ktile = t >> 7, ktl = t & 127;             // K: 128 thr/tile
    const int krow = ktl >> 2, koff = (ktl & 3) * 8;     // 4 thr/row, 32 rows

    float l_i = 0.f;
    float4v acc[4];
#pragma unroll
    for (int s = 0; s < 4; ++s) acc[s] = (float4v){0.f, 0.f, 0.f, 0.f};
    unsigned short* pw = ptl[wv];

    for (int rnd = 0; rnd < 64; ++rnd) {
        const int j0a = rnd * 32;            // jh=0 tile
        const int j0w = jh * 2048 + rnd * 32; // this wave's tile
        // ---- prefetch tile data (global, coalesced) ----
        uint4 v0 = *(const uint4*)(VT + (size_t)(cc0 + vcc) * 4096 + j0a + voff);
        uint4 v1 = *(const uint4*)(VT + (size_t)(cc0 + vcc) * 4096 + 2048 + j0a + voff);
        uint4 kv = *(const uint4*)(Kb + (size_t)(ktile * 2048 + j0a + krow) * 32 + koff);
        __syncthreads();   // WAR: previous round's frag reads done
        *(uint4*)&Vt[0][vcc][voff] = v0;
        *(uint4*)&Vt[1][vcc][voff] = v1;
        *(uint4*)&Kt[ktile][krow][koff] = kv;
        __syncthreads();   // RAW: tiles visible
        // ---- S^T = K Q^T: rows j = quad*4+r, cols q = l15 ----
        short8 kfr0 = *(const short8*)&Kt[jh][l15][quad * 8];
        short8 kfr1 = *(const short8*)&Kt[jh][16 + l15][quad * 8];
        float4v s0 = (float4v){0.f, 0.f, 0.f, 0.f}, s1 = s0;
        s0 = __builtin_amdgcn_mfma_f32_16x16x32_bf16(kfr0, qfr, s0, 0, 0, 0);
        s1 = __builtin_amdgcn_mfma_f32_16x16x32_bf16(kfr1, qfr, s1, 0, 0, 0);
        // ---- max-free softmax numerator ----
        float p[8]; float ls = 0.f;
#pragma unroll
        for (int r = 0; r < 4; ++r) { p[r] = __expf(s0[r] - SM_SHIFT); ls += p[r]; }
#pragma unroll
        for (int r = 0; r < 4; ++r) { p[4 + r] = __expf(s1[r] - SM_SHIFT); ls += p[4 + r]; }
        l_i += ls;
        union { uint2 v; unsigned short u[4]; } pk0, pk1;
#pragma unroll
        for (int r = 0; r < 4; ++r) { pk0.u[r] = f2bf(p[r]); pk1.u[r] = f2bf(p[4 + r]); }
        *(uint2*)&pw[l15 * 40 + (quad << 2)] = pk0.v;        // P[q=l15][j_local=quad*4+r]
        *(uint2*)&pw[l15 * 40 + 16 + (quad << 2)] = pk1.v;   // P[q=l15][16+quad*4+r]
        short8 pfr = *(const short8*)&pw[l15 * 40 + quad * 8];  // A[m=q][k=j] (wave-private)
        // ---- PV from LDS V tile ----
#pragma unroll
        for (int s = 0; s < 4; ++s) {
            short8 vfr = *(const short8*)&Vt[jh][s * 16 + l15][quad * 8];
            acc[s] = __builtin_amdgcn_mfma_f32_16x16x32_bf16(pfr, vfr, acc[s], 0, 0, 0);
        }
    }

    l_i += __shfl_xor(l_i, 16);
    l_i += __shfl_xor(l_i, 32);

    __syncthreads();
    if (jh == 1) {
#pragma unroll
        for (int s = 0; s < 4; ++s) *(float4v*)&red[g][lane][s * 4] = acc[s];
        red[g][lane][16] = l_i;
    }
    __syncthreads();
    if (jh == 0) {
#pragma unroll
        for (int s = 0; s < 4; ++s) {
            float4v o = *(const float4v*)&red[g][lane][s * 4];
            acc[s][0] += o[0]; acc[s][1] += o[1]; acc[s][2] += o[2]; acc[s][3] += o[3];
        }
        l_i += red[g][lane][16];
        float lr[4];
#pragma unroll
        for (int r = 0; r < 4; ++r) lr[r] = __shfl(l_i, (quad << 2) + r);
        const float gm = gamma[0];
        const float* xb = x + (size_t)b * CHW;
        float* ob = out + (size_t)b * CHW;
#pragma unroll
        for (int s = 0; s < 4; ++s) {
#pragma unroll
            for (int r = 0; r < 4; ++r) {
                int q = q0 + (quad << 2) + r;
                int cc = cc0 + s * 16 + l15;
                size_t idx = (size_t)q * 256 + cc;
                ob[idx] = gm * (acc[s][r] / lr[r]) + xb[idx];
            }
        }
    }
}

extern "C" void kernel_launch(void* const* d_in, const int* in_sizes, int n_in,
                              void* d_out, int out_size, void* d_ws, size_t ws_size,
                              hipStream_t stream)
{
    (void)in_sizes; (void)n_in; (void)out_size; (void)ws_size;
    const float* x     = (const float*)d_in[0];
    const float* w_off = (const float*)d_in[1];
    const float* b_off = (const float*)d_in[2];
    const float* wq    = (const float*)d_in[3];
    const float* bq    = (const float*)d_in[4];
    const float* wk    = (const float*)d_in[5];
    const float* bk    = (const float*)d_in[6];
    const float* wv    = (const float*)d_in[7];
    const float* bv    = (const float*)d_in[8];
    const float* gamma = (const float*)d_in[9];
    float* out = (float*)d_out;

    // ws layout (bytes): total 45,942,784 — R3/R7 proven footprint.
    char* ws = (char*)d_ws;
    float*          off_buf = (float*)(ws + 0);                  //  589824
    uint2*          pbw     = (uint2*)(ws + 589824);             //  589824
    uint32_t*       pba     = (uint32_t*)(ws + 1179648);         //  294912
    unsigned short* qb16    = (unsigned short*)(ws + 1474560);   //  524288 [32 c][4096 p] flat
    unsigned short* kb16    = (unsigned short*)(ws + 1998848);   //  524288 [32 c][4096 p] flat
    unsigned short* vb16T   = (unsigned short*)(ws + 2523136);   // 4194304 VT2[cc][j]
    unsigned short* wcat    = (unsigned short*)(ws + 6717440);   // 1474560
    float*          bcat    = (float*)(ws + 8192000);            //    2048
    unsigned short* sbuf    = (unsigned short*)(ws + 8194048);   // 37748736
    // vb16 ([256 c][4096 p] flat) lives in d_out scratch; k_attn later overwrites all of d_out.
    unsigned short* vb16    = (unsigned short*)d_out;

    k_offset_conv<<<dim3(2 * HH), 256, 0, stream>>>(x, w_off, off_buf);
    k_params<<<dim3(2 * HH), 256, 0, stream>>>(off_buf, b_off, pbw, pba);
    k_wcat<<<dim3(720), 256, 0, stream>>>(wq, wk, wv, bq, bk, bv, wcat, bcat);
    k_sample<<<dim3(2 * HH, 4), 256, 0, stream>>>(x, pbw, pba, sbuf);
    k_wgemm<<<dim3(2 * HH, 5), 256, 0, stream>>>(wcat, bcat, sbuf, qb16, kb16, vb16);
    k_vtrans<<<dim3(64, 2), 256, 0, stream>>>(vb16, vb16T);
    k_attn<<<dim3(128, 4, 2), 256, 0, stream>>>(qb16, kb16, vb16T, x, gamma, out);
}

// Round 9
// 293.649 us; speedup vs baseline: 8.6089x; 1.1288x over previous
//
#include <hip/hip_runtime.h>
#include <math.h>
#include <stdint.h>

#define CIN 256
#define HH 64
#define WW 64
#define HW 4096
#define CHW (CIN * HW) // 1048576

typedef __attribute__((ext_vector_type(8))) short short8;   // 8 bf16 = 4 VGPR (MFMA A/B frag)
typedef __attribute__((ext_vector_type(4))) float float4v;  // MFMA C/D frag
typedef __attribute__((ext_vector_type(2))) float f2a;

__device__ inline unsigned short f2bf(float f) {
    union { float f; uint32_t u; } v; v.f = f;
    return (unsigned short)((v.u + 0x7FFFu + ((v.u >> 16) & 1u)) >> 16);
}
__device__ inline float bf2f(unsigned short h) {
    union { uint32_t u; float f; } v; v.u = ((uint32_t)h) << 16;
    return v.f;
}
__device__ inline f2a ldg2(const float* p) {
    f2a r; __builtin_memcpy(&r, p, 8); return r;
}

// ================= Kernel 1: offset conv partials, 8-way channel split ===========================
// grid (128 bh, 8 cg); 256 thr = 4 waves; wave handles 8 channels (c = cg*32 + wv*8 + ci).
// off_part: [8 cg][128 bh][18 co][64 w] = 4,718,592 B, lives in d_out scratch (dead before k_wgemm).
__global__ __launch_bounds__(256) void k_offset_conv(
    const float* __restrict__ x, const float* __restrict__ w_off,
    float* __restrict__ off_part)
{
    __shared__ float red[4][64][18];
    const int bh = blockIdx.x, cg = blockIdx.y;
    const int b = bh >> 6, h = bh & 63;
    const int t = threadIdx.x;
    const int w = t & 63;
    const int wv = __builtin_amdgcn_readfirstlane(t >> 6);
    float acc[18];
#pragma unroll
    for (int i = 0; i < 18; ++i) acc[i] = 0.f;
    const float* xb = x + (size_t)b * CHW;
#pragma unroll
    for (int ci = 0; ci < 8; ++ci) {
        const int c = cg * 32 + wv * 8 + ci;
        const float* xc = xb + (size_t)c * HW;
        float r0 = (h > 0)  ? xc[(h - 1) * WW + w] : 0.f;
        float r1 =            xc[h * WW + w];
        float r2 = (h < 63) ? xc[(h + 1) * WW + w] : 0.f;
        float l0 = __shfl_up(r0, 1), l1 = __shfl_up(r1, 1), l2 = __shfl_up(r2, 1);
        float d0 = __shfl_down(r0, 1), d1 = __shfl_down(r1, 1), d2 = __shfl_down(r2, 1);
        if (w == 0)  { l0 = 0.f; l1 = 0.f; l2 = 0.f; }
        if (w == 63) { d0 = 0.f; d1 = 0.f; d2 = 0.f; }
        const float xv[9] = {l0, r0, d0, l1, r1, d1, l2, r2, d2};
        const float* wc = w_off + (size_t)c * 9;
#pragma unroll
        for (int co = 0; co < 18; ++co) {
            const float* wp = wc + (size_t)co * (CIN * 9);
#pragma unroll
            for (int k = 0; k < 9; ++k) acc[co] += wp[k] * xv[k];
        }
    }
#pragma unroll
    for (int co = 0; co < 18; ++co) red[wv][w][co] = acc[co];
    __syncthreads();
    if (t < 64) {
#pragma unroll
        for (int co = 0; co < 18; ++co) {
            float s = red[0][t][co] + red[1][t][co] + red[2][t][co] + red[3][t][co];
            off_part[((size_t)(cg * 128 + bh)) * 1152 + co * 64 + t] = s;
        }
    }
}

// ================= Kernel 2: patch-form bilinear params (sums 8 conv partials) ===================
__global__ __launch_bounds__(256) void k_params(
    const float* __restrict__ off_part, const float* __restrict__ b_off,
    uint2* __restrict__ pbw, uint32_t* __restrict__ pba)
{
    const int bh = blockIdx.x;
    const int h = bh & 63;
    const int t = threadIdx.x;
    for (int r = 0; r < 3; ++r) {
        int sid = t + 256 * r;
        if (sid < 576) {
            int k = sid >> 6, ww = sid & 63;
            float dy = b_off[2 * k], dx = b_off[2 * k + 1];
#pragma unroll
            for (int g = 0; g < 8; ++g) {
                const float* pp = off_part + (size_t)(g * 128 + bh) * 1152;
                dy += pp[(2 * k) * 64 + ww];
                dx += pp[(2 * k + 1) * 64 + ww];
            }
            float py = (float)(h + k / 3 - 1) + dy;
            float px = (float)(ww + k % 3 - 1) + dx;
            float y0f = floorf(py), x0f = floorf(px);
            float fy = py - y0f, fx = px - x0f;
            int y0 = (int)y0f, x0 = (int)x0f;
            int yb = min(max(y0, 0), 62), xb = min(max(x0, 0), 62);
            float wr[2] = {0.f, 0.f}, wc[2] = {0.f, 0.f};
            if (y0 >= 0 && y0 < HH) wr[y0 - yb] += 1.f - fy;
            if (y0 + 1 >= 0 && y0 + 1 < HH) wr[y0 + 1 - yb] += fy;
            if (x0 >= 0 && x0 < WW) wc[x0 - xb] += 1.f - fx;
            if (x0 + 1 >= 0 && x0 + 1 < WW) wc[x0 + 1 - xb] += fx;
            uint2 pw;
            pw.x = (uint32_t)f2bf(wr[0] * wc[0]) | ((uint32_t)f2bf(wr[0] * wc[1]) << 16);
            pw.y = (uint32_t)f2bf(wr[1] * wc[0]) | ((uint32_t)f2bf(wr[1] * wc[1]) << 16);
            pbw[(size_t)bh * 576 + sid] = pw;
            pba[(size_t)bh * 576 + sid] = (uint32_t)(yb * WW + xb);
        }
    }
}

// ================= Kernel 3: W concat + bf16 cast — R3/R7-proven =================================
__global__ __launch_bounds__(256) void k_wcat(
    const float* __restrict__ wq, const float* __restrict__ wk, const float* __restrict__ wv_,
    const float* __restrict__ bq, const float* __restrict__ bk, const float* __restrict__ bv,
    unsigned short* __restrict__ wcat, float* __restrict__ bcat)
{
    int e = (blockIdx.x * 256 + threadIdx.x) * 4;
    const float* src;
    if (e < 32 * 2304)      src = wq + e;
    else if (e < 64 * 2304) src = wk + (e - 32 * 2304);
    else                    src = wv_ + (e - 64 * 2304);
    float4 v = *(const float4*)src;
    unsigned short o[4] = {f2bf(v.x), f2bf(v.y), f2bf(v.z), f2bf(v.w)};
    *(uint2*)(wcat + e) = *(const uint2*)o;
    if (blockIdx.x == 0 && threadIdx.x < 320) {
        int c = threadIdx.x;
        bcat[c] = c < 32 ? bq[c] : (c < 64 ? bk[c - 32] : bv[c - 64]);
    }
}

// ================= Kernel 4: sample S[n=8192][k=2304] bf16 — R3/R7-proven ========================
__global__ __launch_bounds__(256) void k_sample(
    const float* __restrict__ x, const uint2* __restrict__ pbw,
    const uint32_t* __restrict__ pba, unsigned short* __restrict__ sbuf)
{
    __shared__ uint2 prw[576];
    __shared__ uint32_t pra[576];
    __shared__ uint32_t T32[64 * 37];

    const int bh = blockIdx.x;
    const int cg = blockIdx.y;
    const int b = bh >> 6;
    const int t = threadIdx.x;
    const int p = t & 63;
    const int duo = t >> 6;

    for (int r = 0; r < 3; ++r) {
        int sid = t + 256 * r;
        if (sid < 576) { prw[sid] = pbw[(size_t)bh * 576 + sid]; pra[sid] = pba[(size_t)bh * 576 + sid]; }
    }
    __syncthreads();

    const float* xb = x + (size_t)b * CHW;
    const int fr = t >> 2, fc = t & 3;
    uint32_t* sb32 = (uint32_t*)sbuf;

    for (int c8 = 0; c8 < 8; ++c8) {
        const int ca = cg * 64 + c8 * 8 + duo * 2;
        const float* xpa = xb + (size_t)ca * HW;
        const float* xpb = xpa + HW;
        unsigned short vals[18];
#pragma unroll
        for (int tap = 0; tap < 9; ++tap) {
            uint2 wv2 = prw[tap * 64 + p];
            uint32_t base = pra[tap * 64 + p];
            float w00 = bf2f((unsigned short)(wv2.x & 0xFFFF));
            float w01 = bf2f((unsigned short)(wv2.x >> 16));
            float w10 = bf2f((unsigned short)(wv2.y & 0xFFFF));
            float w11 = bf2f((unsigned short)(wv2.y >> 16));
            f2a a0 = ldg2(xpa + base), a1 = ldg2(xpa + base + WW);
            f2a b0 = ldg2(xpb + base), b1 = ldg2(xpb + base + WW);
            vals[tap]     = f2bf(w00 * a0.x + w01 * a0.y + w10 * a1.x + w11 * a1.y);
            vals[9 + tap] = f2bf(w00 * b0.x + w01 * b0.y + w10 * b1.x + w11 * b1.y);
        }
        __syncthreads();
#pragma unroll
        for (int i = 0; i < 9; ++i)
            T32[p * 37 + duo * 9 + i] = (uint32_t)vals[2 * i] | ((uint32_t)vals[2 * i + 1] << 16);
        __syncthreads();
        {
            size_t gb = (size_t)(bh * 64 + fr) * 1152 + cg * 288 + c8 * 36 + fc * 9;
            const uint32_t* Tr = &T32[fr * 37 + fc * 9];
            uint32_t* gp = sb32 + gb;
#pragma unroll
            for (int i = 0; i < 9; ++i) gp[i] = Tr[i];
        }
    }
}

// ================= Kernel 5: GEMM C[320][8192] = Wcat . S^T — R3/R7-proven =======================
__global__ __launch_bounds__(256) void k_wgemm(
    const unsigned short* __restrict__ wcat, const float* __restrict__ bcat,
    const unsigned short* __restrict__ sbuf,
    unsigned short* __restrict__ qb16, unsigned short* __restrict__ kb16,
    unsigned short* __restrict__ vb16)
{
    __shared__ unsigned short Aw[64 * 36];
    __shared__ unsigned short Bl[64 * 36];

    const int nt = blockIdx.x;
    const int mt = blockIdx.y;
    const int t = threadIdx.x;
    const int lane = t & 63;
    const int l15 = lane & 15, quad = lane >> 4;
    const int wv = __builtin_amdgcn_readfirstlane(t >> 6);

    const int srow = t >> 2, sch = t & 3;
    const unsigned short* Ag = wcat + (size_t)(mt * 64 + srow) * 2304 + sch * 8;
    const unsigned short* Bg = sbuf + (size_t)(nt * 64 + srow) * 2304 + sch * 8;

    float4v acc[4];
#pragma unroll
    for (int s = 0; s < 4; ++s) acc[s] = (float4v){0.f, 0.f, 0.f, 0.f};

    for (int k0 = 0; k0 < 2304; k0 += 32) {
        uint4 av = *(const uint4*)(Ag + k0);
        uint4 bv = *(const uint4*)(Bg + k0);
        __syncthreads();
        *(uint4*)&Aw[srow * 36 + sch * 8] = av;
        *(uint4*)&Bl[srow * 36 + sch * 8] = bv;
        __syncthreads();
        short8 afr = *(const short8*)&Aw[(wv * 16 + l15) * 36 + quad * 8];
#pragma unroll
        for (int s = 0; s < 4; ++s) {
            short8 bfr = *(const short8*)&Bl[(s * 16 + l15) * 36 + quad * 8];
            acc[s] = __builtin_amdgcn_mfma_f32_16x16x32_bf16(afr, bfr, acc[s], 0, 0, 0);
        }
    }

    const int cobase = mt * 64 + wv * 16;
    unsigned short* ob; int lco; size_t nper;
    if (cobase < 32)      { ob = qb16; lco = cobase;      nper = (size_t)32 * HW; }
    else if (cobase < 64) { ob = kb16; lco = cobase - 32; nper = (size_t)32 * HW; }
    else                  { ob = vb16; lco = cobase - 64; nper = (size_t)256 * HW; }
    const int b = nt >> 6;
    unsigned short* obb = ob + (size_t)b * nper;
    float bias_r[4];
#pragma unroll
    for (int r = 0; r < 4; ++r) bias_r[r] = bcat[cobase + (quad << 2) + r];
    const int pb = (nt & 63) * 64;
#pragma unroll
    for (int s = 0; s < 4; ++s) {
#pragma unroll
        for (int r = 0; r < 4; ++r) {
            obb[(size_t)(lco + (quad << 2) + r) * HW + pb + s * 16 + l15]
                = f2bf(acc[s][r] + bias_r[r]);
        }
    }
}

// ================= Kernel 6: V re-layout — R2/R3/R7-proven =======================================
__global__ __launch_bounds__(256) void k_vtrans(
    const unsigned short* __restrict__ vb16, unsigned short* __restrict__ vb16T)
{
    const int jt = blockIdx.x, b = blockIdx.y;
    const int cc = threadIdx.x;
    const unsigned short* src = vb16 + (size_t)b * CHW + (size_t)(jt * 64) * 256 + cc;
    unsigned short* dst = vb16T + (size_t)b * CHW + (size_t)cc * 4096 + jt * 64;
#pragma unroll
    for (int o = 0; o < 8; ++o) {
        union { uint4 v; unsigned short u[8]; } tmp;
#pragma unroll
        for (int j = 0; j < 8; ++j) tmp.u[j] = src[(o * 8 + j) * 256];
        *(uint4*)(dst + o * 8) = tmp.v;
    }
}

// ================= Kernel 7: flash attention with LDS-staged K/V tiles — R8-proven ===============
#define SM_SHIFT 16.0f
__global__ __launch_bounds__(256) void k_attn(
    const unsigned short* __restrict__ qb16, const unsigned short* __restrict__ kb16,
    const unsigned short* __restrict__ vt, const float* __restrict__ x,
    const float* __restrict__ gamma, float* __restrict__ out)
{
    __shared__ unsigned short ptl[4][16 * 40];
    __shared__ unsigned short Vt[2][64][40];
    __shared__ unsigned short Kt[2][32][36];
    __shared__ float red[2][64][20];

    const int qt = blockIdx.x, ch = blockIdx.y, b = blockIdx.z;
    const int t = threadIdx.x;
    const int lane = t & 63;
    const int wv = t >> 6;
    const int g = wv & 1, jh = wv >> 1;
    const int l15 = lane & 15, quad = lane >> 4;
    const int cc0 = ch * 64;

    const unsigned short* Qb = qb16 + (size_t)b * (32 * 4096);
    const unsigned short* Kb = kb16 + (size_t)b * (32 * 4096);
    const unsigned short* VT = vt + (size_t)b * CHW;

    const int q0 = qt * 32 + g * 16;
    short8 qfr = *(const short8*)(Qb + (size_t)(q0 + l15) * 32 + quad * 8);

    const int vcc = t >> 2, voff = (t & 3) * 8;
    const int ktile = t >> 7, ktl = t & 127;
    const int krow = ktl >> 2, koff = (ktl & 3) * 8;

    float l_i = 0.f;
    float4v acc[4];
#pragma unroll
    for (int s = 0; s < 4; ++s) acc[s] = (float4v){0.f, 0.f, 0.f, 0.f};
    unsigned short* pw = ptl[wv];

    for (int rnd = 0; rnd < 64; ++rnd) {
        const int j0a = rnd * 32;
        uint4 v0 = *(const uint4*)(VT + (size_t)(cc0 + vcc) * 4096 + j0a + voff);
        uint4 v1 = *(const uint4*)(VT + (size_t)(cc0 + vcc) * 4096 + 2048 + j0a + voff);
        uint4 kv = *(const uint4*)(Kb + (size_t)(ktile * 2048 + j0a + krow) * 32 + koff);
        __syncthreads();
        *(uint4*)&Vt[0][vcc][voff] = v0;
        *(uint4*)&Vt[1][vcc][voff] = v1;
        *(uint4*)&Kt[ktile][krow][koff] = kv;
        __syncthreads();
        short8 kfr0 = *(const short8*)&Kt[jh][l15][quad * 8];
        short8 kfr1 = *(const short8*)&Kt[jh][16 + l15][quad * 8];
        float4v s0 = (float4v){0.f, 0.f, 0.f, 0.f}, s1 = s0;
        s0 = __builtin_amdgcn_mfma_f32_16x16x32_bf16(kfr0, qfr, s0, 0, 0, 0);
        s1 = __builtin_amdgcn_mfma_f32_16x16x32_bf16(kfr1, qfr, s1, 0, 0, 0);
        float p[8]; float ls = 0.f;
#pragma unroll
        for (int r = 0; r < 4; ++r) { p[r] = __expf(s0[r] - SM_SHIFT); ls += p[r]; }
#pragma unroll
        for (int r = 0; r < 4; ++r) { p[4 + r] = __expf(s1[r] - SM_SHIFT); ls += p[4 + r]; }
        l_i += ls;
        union { uint2 v; unsigned short u[4]; } pk0, pk1;
#pragma unroll
        for (int r = 0; r < 4; ++r) { pk0.u[r] = f2bf(p[r]); pk1.u[r] = f2bf(p[4 + r]); }
        *(uint2*)&pw[l15 * 40 + (quad << 2)] = pk0.v;
        *(uint2*)&pw[l15 * 40 + 16 + (quad << 2)] = pk1.v;
        short8 pfr = *(const short8*)&pw[l15 * 40 + quad * 8];
#pragma unroll
        for (int s = 0; s < 4; ++s) {
            short8 vfr = *(const short8*)&Vt[jh][s * 16 + l15][quad * 8];
            acc[s] = __builtin_amdgcn_mfma_f32_16x16x32_bf16(pfr, vfr, acc[s], 0, 0, 0);
        }
    }

    l_i += __shfl_xor(l_i, 16);
    l_i += __shfl_xor(l_i, 32);

    __syncthreads();
    if (jh == 1) {
#pragma unroll
        for (int s = 0; s < 4; ++s) *(float4v*)&red[g][lane][s * 4] = acc[s];
        red[g][lane][16] = l_i;
    }
    __syncthreads();
    if (jh == 0) {
#pragma unroll
        for (int s = 0; s < 4; ++s) {
            float4v o = *(const float4v*)&red[g][lane][s * 4];
            acc[s][0] += o[0]; acc[s][1] += o[1]; acc[s][2] += o[2]; acc[s][3] += o[3];
        }
        l_i += red[g][lane][16];
        float lr[4];
#pragma unroll
        for (int r = 0; r < 4; ++r) lr[r] = __shfl(l_i, (quad << 2) + r);
        const float gm = gamma[0];
        const float* xb = x + (size_t)b * CHW;
        float* ob = out + (size_t)b * CHW;
#pragma unroll
        for (int s = 0; s < 4; ++s) {
#pragma unroll
            for (int r = 0; r < 4; ++r) {
                int q = q0 + (quad << 2) + r;
                int cc = cc0 + s * 16 + l15;
                size_t idx = (size_t)q * 256 + cc;
                ob[idx] = gm * (acc[s][r] / lr[r]) + xb[idx];
            }
        }
    }
}

extern "C" void kernel_launch(void* const* d_in, const int* in_sizes, int n_in,
                              void* d_out, int out_size, void* d_ws, size_t ws_size,
                              hipStream_t stream)
{
    (void)in_sizes; (void)n_in; (void)out_size; (void)ws_size;
    const float* x     = (const float*)d_in[0];
    const float* w_off = (const float*)d_in[1];
    const float* b_off = (const float*)d_in[2];
    const float* wq    = (const float*)d_in[3];
    const float* bq    = (const float*)d_in[4];
    const float* wk    = (const float*)d_in[5];
    const float* bk    = (const float*)d_in[6];
    const float* wv    = (const float*)d_in[7];
    const float* bv    = (const float*)d_in[8];
    const float* gamma = (const float*)d_in[9];
    float* out = (float*)d_out;

    // ws layout (bytes): R7/R8-proven footprint (off_buf region now unused; off_part -> d_out).
    char* ws = (char*)d_ws;
    uint2*          pbw     = (uint2*)(ws + 589824);             //  589824
    uint32_t*       pba     = (uint32_t*)(ws + 1179648);         //  294912
    unsigned short* qb16    = (unsigned short*)(ws + 1474560);   //  524288 [32 c][4096 p] flat
    unsigned short* kb16    = (unsigned short*)(ws + 1998848);   //  524288 [32 c][4096 p] flat
    unsigned short* vb16T   = (unsigned short*)(ws + 2523136);   // 4194304 VT2[cc][j]
    unsigned short* wcat    = (unsigned short*)(ws + 6717440);   // 1474560
    float*          bcat    = (float*)(ws + 8192000);            //    2048
    unsigned short* sbuf    = (unsigned short*)(ws + 8194048);   // 37748736
    // d_out scratch (8 MB), time-sliced: off_part (4.72 MB) until k_params; then vb16 (4 MB)
    // until k_vtrans; k_attn overwrites all of d_out last.
    float*          off_part = (float*)d_out;
    unsigned short* vb16     = (unsigned short*)d_out;

    k_offset_conv<<<dim3(128, 8), 256, 0, stream>>>(x, w_off, off_part);
    k_params<<<dim3(128), 256, 0, stream>>>(off_part, b_off, pbw, pba);
    k_wcat<<<dim3(720), 256, 0, stream>>>(wq, wk, wv, bq, bk, bv, wcat, bcat);
    k_sample<<<dim3(2 * HH, 4), 256, 0, stream>>>(x, pbw, pba, sbuf);
    k_wgemm<<<dim3(2 * HH, 5), 256, 0, stream>>>(wcat, bcat, sbuf, qb16, kb16, vb16);
    k_vtrans<<<dim3(64, 2), 256, 0, stream>>>(vb16, vb16T);
    k_attn<<<dim3(128, 4, 2), 256, 0, stream>>>(qb16, kb16, vb16T, x, gamma, out);
}